// Round 3
// baseline (10386.080 us; speedup 1.0000x reference)
//
#include <hip/hip_runtime.h>
#include <hip/hip_bf16.h>
#include <math.h>

#define B_ 2
#define L_ 2048
#define C_ 1024
#define H_ 16
#define D_ 64

// ---------------------------------------------------------------------------
// Kernel 1: m = silu(mod) @ w_mod + b_mod   → fp32 [2, 6144] in ws
// All inputs fp32 (reference dtype).
__global__ __launch_bounds__(256) void k_mod(const float* __restrict__ mod,
                                             const float* __restrict__ w_mod,
                                             const float* __restrict__ b_mod,
                                             float* __restrict__ m_out) {
    __shared__ float a_s[2][C_];
    for (int i = threadIdx.x; i < 2 * C_; i += 256) {
        float a = mod[i];
        a_s[i >> 10][i & (C_ - 1)] = a / (1.f + __expf(-a));  // silu
    }
    __syncthreads();
    int j = blockIdx.x * 256 + threadIdx.x;  // 0..6143
    float acc0 = b_mod[j];
    float acc1 = acc0;
    for (int k = 0; k < C_; ++k) {
        float w = w_mod[(size_t)k * (6 * C_) + j];
        acc0 += a_s[0][k] * w;
        acc1 += a_s[1][k] * w;
    }
    m_out[j] = acc0;
    m_out[6 * C_ + j] = acc1;
}

// ---------------------------------------------------------------------------
// Kernel 2: LayerNorm (eps 1e-6, no affine) + adaLN modulate → bf16 h
// input fp32 (feats or x1), output bf16 workspace
__global__ __launch_bounds__(256) void k_ln_mod(const float* __restrict__ x,
                                                const float* __restrict__ mvec,
                                                int off_sh, int off_sc,
                                                __hip_bfloat16* __restrict__ h_out) {
    int row = blockIdx.x;       // 0..4095
    int b = row / L_;
    int t = threadIdx.x;
    float v[4];
    float s = 0.f, ss = 0.f;
#pragma unroll
    for (int i = 0; i < 4; ++i) {
        int c = t + i * 256;
        float val = x[(size_t)row * C_ + c];
        v[i] = val; s += val; ss += val * val;
    }
#pragma unroll
    for (int o = 32; o; o >>= 1) { s += __shfl_xor(s, o); ss += __shfl_xor(ss, o); }
    __shared__ float red[2][4];
    int wid = t >> 6, lane = t & 63;
    if (lane == 0) { red[0][wid] = s; red[1][wid] = ss; }
    __syncthreads();
    s  = red[0][0] + red[0][1] + red[0][2] + red[0][3];
    ss = red[1][0] + red[1][1] + red[1][2] + red[1][3];
    float mean = s * (1.f / C_);
    float var  = ss * (1.f / C_) - mean * mean;
    float rstd = rsqrtf(var + 1e-6f);
#pragma unroll
    for (int i = 0; i < 4; ++i) {
        int c = t + i * 256;
        float sc = mvec[b * (6 * C_) + off_sc + c];
        float sh = mvec[b * (6 * C_) + off_sh + c];
        float hn = (v[i] - mean) * rstd;
        h_out[(size_t)row * C_ + c] = __float2bfloat16(hn * (1.f + sc) + sh);
    }
}

// ---------------------------------------------------------------------------
// Kernel 3: tiled GEMM  v = A[M,K](lda, bf16) @ W[K,N](ldw, fp32) + bias(fp32)
//   act==1: v = gelu_exact(v)
//   emode 0: store v (out_bf or out_f)
//   emode 2: v = resid_f + v*gate[b,n]; store (out_bf or out_f)
//   emode 3: out_f[m,n] += v*gate[b,n]
// 64x64 tile, block (16,16), 4x4 per thread, K-tile 16.
__global__ __launch_bounds__(256) void k_gemm(const __hip_bfloat16* __restrict__ A, int lda,
                                              const float* __restrict__ Wm, int ldw,
                                              const float* __restrict__ bias,
                                              int M, int N, int K, int act, int emode,
                                              const float* __restrict__ gate,
                                              const float* __restrict__ resid_f,
                                              __hip_bfloat16* __restrict__ out_bf,
                                              float* __restrict__ out_f) {
    __shared__ float As[16][65];
    __shared__ float Bs[16][65];
    int tx = threadIdx.x, ty = threadIdx.y;
    int t = ty * 16 + tx;
    int m0 = blockIdx.y * 64;
    int n0 = blockIdx.x * 64;
    float acc[4][4] = {};
    for (int k0 = 0; k0 < K; k0 += 16) {
        {   // A tile: 64 rows x 16 k (bf16 source)
            int row = t >> 2;
            int kc = (t & 3) * 4;
            const __hip_bfloat16* ap = A + (size_t)(m0 + row) * lda + k0 + kc;
#pragma unroll
            for (int j = 0; j < 4; ++j) As[kc + j][row] = __bfloat162float(ap[j]);
        }
        {   // B tile: 16 k x 64 cols (fp32 source)
            int kr = t >> 4;
            int nc = (t & 15) * 4;
            const float* bp = Wm + (size_t)(k0 + kr) * ldw + n0 + nc;
#pragma unroll
            for (int j = 0; j < 4; ++j) Bs[kr][nc + j] = bp[j];
        }
        __syncthreads();
#pragma unroll
        for (int kk = 0; kk < 16; ++kk) {
            float a[4], b[4];
#pragma unroll
            for (int i = 0; i < 4; ++i) a[i] = As[kk][ty * 4 + i];
#pragma unroll
            for (int i = 0; i < 4; ++i) b[i] = Bs[kk][tx * 4 + i];
#pragma unroll
            for (int i = 0; i < 4; ++i)
#pragma unroll
                for (int j = 0; j < 4; ++j) acc[i][j] += a[i] * b[j];
        }
        __syncthreads();
    }
#pragma unroll
    for (int i = 0; i < 4; ++i) {
        int m = m0 + ty * 4 + i;
        int bidx = m / L_;
#pragma unroll
        for (int j = 0; j < 4; ++j) {
            int n = n0 + tx * 4 + j;
            float v = acc[i][j] + (bias ? bias[n] : 0.f);
            if (act == 1) v = 0.5f * v * (1.f + erff(v * 0.70710678118654752440f));
            if (emode == 2) {
                float g = gate[bidx * (6 * C_) + n];
                v = resid_f[(size_t)m * N + n] + v * g;
            } else if (emode == 3) {
                float g = gate[bidx * (6 * C_) + n];
                out_f[(size_t)m * N + n] += v * g;
                continue;
            }
            if (out_f) out_f[(size_t)m * N + n] = v;
            else       out_bf[(size_t)m * N + n] = __float2bfloat16(v);
        }
    }
}

// ---------------------------------------------------------------------------
// Kernel 4: flash-style attention. One wave per (b,h,q) row, lane = d (D=64).
// qkv bf16 workspace [4096, 3072], o bf16 workspace [4096, 1024].
__global__ __launch_bounds__(256) void k_attn(const __hip_bfloat16* __restrict__ qkv,
                                              __hip_bfloat16* __restrict__ o) {
    int lane = threadIdx.x & 63;
    int wid = threadIdx.x >> 6;
    int task = blockIdx.x * 4 + wid;        // ((b*H + h)*L + q)
    int q = task & (L_ - 1);
    int bh = task >> 11;
    int h = bh & (H_ - 1);
    int b = bh >> 4;
    int row_base = b * L_;
    const size_t stride = 3 * C_;
    float qv = __bfloat162float(qkv[(size_t)(row_base + q) * stride + h * D_ + lane]) * 0.125f;
    const __hip_bfloat16* kbase = qkv + (size_t)row_base * stride + C_ + h * D_ + lane;
    const __hip_bfloat16* vbase = qkv + (size_t)row_base * stride + 2 * C_ + h * D_ + lane;
    float m_run = -1e30f, l_run = 0.f, acc = 0.f;
    for (int kk = 0; kk < L_; ++kk) {
        float kv = __bfloat162float(kbase[(size_t)kk * stride]);
        float s = qv * kv;
#pragma unroll
        for (int o2 = 32; o2; o2 >>= 1) s += __shfl_xor(s, o2);
        float vv = __bfloat162float(vbase[(size_t)kk * stride]);
        float m_new = fmaxf(m_run, s);
        float alpha = __expf(m_run - m_new);
        float p = __expf(s - m_new);
        l_run = l_run * alpha + p;
        acc = acc * alpha + p * vv;
        m_run = m_new;
    }
    o[(size_t)(row_base + q) * C_ + h * D_ + lane] = __float2bfloat16(acc / l_run);
}

// ---------------------------------------------------------------------------
extern "C" void kernel_launch(void* const* d_in, const int* in_sizes, int n_in,
                              void* d_out, int out_size, void* d_ws, size_t ws_size,
                              hipStream_t stream) {
    const float* feats  = (const float*)d_in[0];
    const float* mod    = (const float*)d_in[1];
    const float* w_mod  = (const float*)d_in[2];
    const float* b_mod  = (const float*)d_in[3];
    const float* w_qkv  = (const float*)d_in[4];
    const float* b_qkv  = (const float*)d_in[5];
    const float* w_proj = (const float*)d_in[6];
    const float* b_proj = (const float*)d_in[7];
    const float* w_fc1  = (const float*)d_in[8];
    const float* b_fc1  = (const float*)d_in[9];
    const float* w_fc2  = (const float*)d_in[10];
    const float* b_fc2  = (const float*)d_in[11];

    const int M = B_ * L_;          // 4096

    // Workspace (peak ~40.1 MB, liveness-overlaid):
    //   m:     [0, 48K)                 fp32 [2,6144], live whole pass
    //   slotB: [48K, +24M)              qkv bf16 (steps 3-4), then x1 fp32 16MB (5-8)
    //   slotA: [48K+24M, +8M)           h1 (2-3), o (4-5), h2 (6-7)  bf16 [4096,1024]
    //   slotC: [48K+32M, +8M)           hf chunk bf16 [4096,1024] (step 7)
    char* ws = (char*)d_ws;
    float* m_ws = (float*)ws;
    char* slotB = ws + 49152;
    __hip_bfloat16* qkv_ws = (__hip_bfloat16*)slotB;
    float* x1_ws           = (float*)slotB;
    __hip_bfloat16* slotA  = (__hip_bfloat16*)(slotB + (size_t)M * 3 * C_ * 2);
    __hip_bfloat16* slotC  = slotA + (size_t)M * C_;

    // 1. modulation vectors
    k_mod<<<dim3(24), 256, 0, stream>>>(mod, w_mod, b_mod, m_ws);
    // 2. h1 = modulate(LN(feats))  [sh_a @ 0, sc_a @ 1024]
    k_ln_mod<<<M, 256, 0, stream>>>(feats, m_ws, 0, 1024, slotA);
    // 3. qkv = h1 @ w_qkv + b_qkv
    k_gemm<<<dim3(3 * C_ / 64, M / 64), dim3(16, 16), 0, stream>>>(
        slotA, C_, w_qkv, 3 * C_, b_qkv, M, 3 * C_, C_, 0, 0,
        nullptr, nullptr, qkv_ws, nullptr);
    // 4. o = attention(qkv)   (slotA: h1 dead, reuse for o)
    k_attn<<<B_ * H_ * L_ / 4, 256, 0, stream>>>(qkv_ws, slotA);
    // 5. x1 = feats + (o @ w_proj + b_proj) * g_a   (g_a @ 2048; x1 overwrites dead qkv)
    k_gemm<<<dim3(C_ / 64, M / 64), dim3(16, 16), 0, stream>>>(
        slotA, C_, w_proj, C_, b_proj, M, C_, C_, 0, 2,
        m_ws + 2 * C_, feats, nullptr, x1_ws);
    // 6. h2 = modulate(LN(x1))  [sh_m @ 3072, sc_m @ 4096]  (slotA: o dead, reuse)
    k_ln_mod<<<M, 256, 0, stream>>>(x1_ws, m_ws, 3 * C_, 4 * C_, slotA);
    // 7. FFN, K-chunked over the 4096 hidden dim (4 chunks of 1024):
    //    hf_c = gelu(h2 @ w_fc1[:, c*1024:(c+1)*1024] + b_fc1_c)
    //    x1  += (hf_c @ w_fc2[c*1024:(c+1)*1024, :] [+ b_fc2 on c==0]) * g_m
    //    last chunk: d_out = x1 + v * g_m  (fp32 output)
    for (int c = 0; c < 4; ++c) {
        k_gemm<<<dim3(C_ / 64, M / 64), dim3(16, 16), 0, stream>>>(
            slotA, C_, w_fc1 + c * C_, 4 * C_, b_fc1 + c * C_, M, C_, C_, 1, 0,
            nullptr, nullptr, slotC, nullptr);
        if (c < 3) {
            k_gemm<<<dim3(C_ / 64, M / 64), dim3(16, 16), 0, stream>>>(
                slotC, C_, w_fc2 + (size_t)c * C_ * C_, C_, (c == 0 ? b_fc2 : nullptr),
                M, C_, C_, 0, 3, m_ws + 5 * C_, nullptr, nullptr, x1_ws);
        } else {
            k_gemm<<<dim3(C_ / 64, M / 64), dim3(16, 16), 0, stream>>>(
                slotC, C_, w_fc2 + (size_t)c * C_ * C_, C_, nullptr,
                M, C_, C_, 0, 2, m_ws + 5 * C_, x1_ws, nullptr, (float*)d_out);
        }
    }
}

// Round 4
// 1724.537 us; speedup vs baseline: 6.0225x; 6.0225x over previous
//
#include <hip/hip_runtime.h>
#include <hip/hip_bf16.h>
#include <math.h>

#define B_ 2
#define L_ 2048
#define C_ 1024
#define H_ 16
#define D_ 64

typedef __attribute__((ext_vector_type(8))) short short8;   // 8 bf16 = 16B (4 VGPRs)
typedef __attribute__((ext_vector_type(4))) float float4v;

__device__ inline float bf2f(short s) {
    union { __hip_bfloat16 h; short s; } u; u.s = s; return __bfloat162float(u.h);
}
__device__ inline short f2bs(float f) {
    union { __hip_bfloat16 h; short s; } u; u.h = __float2bfloat16(f); return u.s;
}

// ---------------------------------------------------------------------------
// Kernel 1: m = silu(mod) @ w_mod + b_mod   → fp32 [2, 6144] in ws
__global__ __launch_bounds__(256) void k_mod(const float* __restrict__ mod,
                                             const float* __restrict__ w_mod,
                                             const float* __restrict__ b_mod,
                                             float* __restrict__ m_out) {
    __shared__ float a_s[2][C_];
    for (int i = threadIdx.x; i < 2 * C_; i += 256) {
        float a = mod[i];
        a_s[i >> 10][i & (C_ - 1)] = a / (1.f + __expf(-a));  // silu
    }
    __syncthreads();
    int j = blockIdx.x * 256 + threadIdx.x;  // 0..6143
    float acc0 = b_mod[j];
    float acc1 = acc0;
    for (int k = 0; k < C_; ++k) {
        float w = w_mod[(size_t)k * (6 * C_) + j];
        acc0 += a_s[0][k] * w;
        acc1 += a_s[1][k] * w;
    }
    m_out[j] = acc0;
    m_out[6 * C_ + j] = acc1;
}

// ---------------------------------------------------------------------------
// Kernel 2: LayerNorm (eps 1e-6, no affine) + adaLN modulate → bf16 h
__global__ __launch_bounds__(256) void k_ln_mod(const float* __restrict__ x,
                                                const float* __restrict__ mvec,
                                                int off_sh, int off_sc,
                                                __hip_bfloat16* __restrict__ h_out) {
    int row = blockIdx.x;       // 0..4095
    int b = row / L_;
    int t = threadIdx.x;
    float v[4];
    float s = 0.f, ss = 0.f;
#pragma unroll
    for (int i = 0; i < 4; ++i) {
        int c = t + i * 256;
        float val = x[(size_t)row * C_ + c];
        v[i] = val; s += val; ss += val * val;
    }
#pragma unroll
    for (int o = 32; o; o >>= 1) { s += __shfl_xor(s, o); ss += __shfl_xor(ss, o); }
    __shared__ float red[2][4];
    int wid = t >> 6, lane = t & 63;
    if (lane == 0) { red[0][wid] = s; red[1][wid] = ss; }
    __syncthreads();
    s  = red[0][0] + red[0][1] + red[0][2] + red[0][3];
    ss = red[1][0] + red[1][1] + red[1][2] + red[1][3];
    float mean = s * (1.f / C_);
    float var  = ss * (1.f / C_) - mean * mean;
    float rstd = rsqrtf(var + 1e-6f);
#pragma unroll
    for (int i = 0; i < 4; ++i) {
        int c = t + i * 256;
        float sc = mvec[b * (6 * C_) + off_sc + c];
        float sh = mvec[b * (6 * C_) + off_sh + c];
        float hn = (v[i] - mean) * rstd;
        h_out[(size_t)row * C_ + c] = __float2bfloat16(hn * (1.f + sc) + sh);
    }
}

// ---------------------------------------------------------------------------
// Kernel 3: MFMA GEMM  v = A[M,K](lda, bf16) @ W[K,N](ldw, fp32→bf16) + bias(f32)
// 128x128 tile, BK=32, 4 waves (2x2 of 64x64), mfma_f32_16x16x32_bf16.
// A_lds/B_lds stored [dim][k] with k-contiguous rows padded 32→40 bf16.
//   act==1: gelu_exact;  emode 0: store; 2: resid_f + v*gate; 3: out_f += v*gate
__global__ __launch_bounds__(256) void k_gemm_mfma(
        const __hip_bfloat16* __restrict__ A, int lda,
        const float* __restrict__ Wm, int ldw,
        const float* __restrict__ bias,
        int M, int N, int K, int act, int emode,
        const float* __restrict__ gate,
        const float* __restrict__ resid_f,
        __hip_bfloat16* __restrict__ out_bf,
        float* __restrict__ out_f) {
    __shared__ short A_lds[128 * 40];
    __shared__ short B_lds[128 * 40];
    const int t = threadIdx.x;
    const int lane = t & 63;
    const int w = t >> 6;
    const int wm = w >> 1, wn = w & 1;
    const int quad = lane >> 4, l16 = lane & 15;
    const int m0 = blockIdx.y * 128;
    const int n0 = blockIdx.x * 128;

    float4v acc[4][4] = {};

    // staging indices
    const int a_row0 = t >> 2;             // +0 / +64
    const int a_kc = (t & 3) * 8;
    const int b_n = t & 127;
    const int b_kg = (t >> 7) * 16;

    for (int k0 = 0; k0 < K; k0 += 32) {
        __syncthreads();   // previous iteration's frag reads done
        // --- stage A: 128 rows x 32 k (bf16, direct 16B copies) ---
#pragma unroll
        for (int rep = 0; rep < 2; ++rep) {
            int row = a_row0 + rep * 64;
            short8 av = *(const short8*)(A + (size_t)(m0 + row) * lda + k0 + a_kc);
            *(short8*)(&A_lds[row * 40 + a_kc]) = av;
        }
        // --- stage B: transpose 32 k x 128 n, fp32 → bf16 ---
#pragma unroll
        for (int rep = 0; rep < 2; ++rep) {
            int kb = b_kg + rep * 8;
            short8 bv;
#pragma unroll
            for (int j = 0; j < 8; ++j)
                bv[j] = f2bs(Wm[(size_t)(k0 + kb + j) * ldw + n0 + b_n]);
            *(short8*)(&B_lds[b_n * 40 + kb]) = bv;
        }
        __syncthreads();
        // --- fragments + MFMA ---
        short8 af[4], bf[4];
#pragma unroll
        for (int mi = 0; mi < 4; ++mi)
            af[mi] = *(const short8*)(&A_lds[(wm * 64 + mi * 16 + l16) * 40 + quad * 8]);
#pragma unroll
        for (int ni = 0; ni < 4; ++ni)
            bf[ni] = *(const short8*)(&B_lds[(wn * 64 + ni * 16 + l16) * 40 + quad * 8]);
#pragma unroll
        for (int mi = 0; mi < 4; ++mi)
#pragma unroll
            for (int ni = 0; ni < 4; ++ni)
                acc[mi][ni] = __builtin_amdgcn_mfma_f32_16x16x32_bf16(
                    af[mi], bf[ni], acc[mi][ni], 0, 0, 0);
    }

    // --- epilogue: C layout col=lane&15, row=quad*4+reg ---
#pragma unroll
    for (int mi = 0; mi < 4; ++mi) {
#pragma unroll
        for (int ni = 0; ni < 4; ++ni) {
#pragma unroll
            for (int r = 0; r < 4; ++r) {
                int m = m0 + wm * 64 + mi * 16 + quad * 4 + r;
                int n = n0 + wn * 64 + ni * 16 + l16;
                float v = acc[mi][ni][r] + (bias ? bias[n] : 0.f);
                if (act == 1) v = 0.5f * v * (1.f + erff(v * 0.70710678118654752440f));
                if (emode == 2) {
                    float g = gate[(m >> 11) * (6 * C_) + n];
                    v = resid_f[(size_t)m * N + n] + v * g;
                } else if (emode == 3) {
                    float g = gate[(m >> 11) * (6 * C_) + n];
                    out_f[(size_t)m * N + n] += v * g;
                    continue;
                }
                if (out_f) out_f[(size_t)m * N + n] = v;
                else       out_bf[(size_t)m * N + n] = __float2bfloat16(v);
            }
        }
    }
}

// ---------------------------------------------------------------------------
// Kernel 4: attention, restructured. One wave per (b, h, 4 queries).
// Per 64-key tile: lane=key computes 4 scores densely; 1 shuffle-reduction
// set per tile (not per key); PV via wave-private LDS transpose, lane=d.
__global__ __launch_bounds__(256) void k_attn(const __hip_bfloat16* __restrict__ qkv,
                                              __hip_bfloat16* __restrict__ o) {
    __shared__ float q_lds[4][D_ * 4];   // [wave][d*4 + iq]
    __shared__ float p_lds[4][64 * 4];   // [wave][key*4 + iq]
    const int lane = threadIdx.x & 63;
    const int wid = threadIdx.x >> 6;
    const int wtask = blockIdx.x * 4 + wid;     // 0..16383
    const int q0 = (wtask & 511) * 4;           // query base (L/4 groups)
    const int bh = wtask >> 9;
    const int h = bh & (H_ - 1);
    const int b = bh >> 4;
    const size_t stride = 3 * C_;
    const size_t row0 = (size_t)b * L_ * stride;

    // load this wave's 4 queries into LDS, scaled by 1/sqrt(D)=0.125
    {
        float4v qv;
#pragma unroll
        for (int iq = 0; iq < 4; ++iq)
            qv[iq] = __bfloat162float(qkv[row0 + (size_t)(q0 + iq) * stride + h * D_ + lane]) * 0.125f;
        *(float4v*)(&q_lds[wid][lane * 4]) = qv;
    }
    __syncthreads();

    const __hip_bfloat16* kp = qkv + row0 + C_ + h * D_;          // + key*stride
    const __hip_bfloat16* vp = qkv + row0 + 2 * C_ + h * D_ + lane;

    float m_run[4], l_run[4], o_acc[4];
#pragma unroll
    for (int iq = 0; iq < 4; ++iq) { m_run[iq] = -3.0e38f; l_run[iq] = 0.f; o_acc[iq] = 0.f; }

    for (int kt = 0; kt < L_; kt += 64) {
        // ---- scores: lane = key kt+lane ----
        float s[4] = {0.f, 0.f, 0.f, 0.f};
        const short8* krow = (const short8*)(kp + (size_t)(kt + lane) * stride);
#pragma unroll
        for (int j = 0; j < 8; ++j) {
            short8 kv8 = krow[j];
#pragma unroll
            for (int c = 0; c < 8; ++c) {
                float kv = bf2f(kv8[c]);
                float4v qv = *(const float4v*)(&q_lds[wid][(j * 8 + c) * 4]);
#pragma unroll
                for (int iq = 0; iq < 4; ++iq) s[iq] += qv[iq] * kv;
            }
        }
        // ---- online softmax (once per 64 keys) ----
        float tmax[4];
#pragma unroll
        for (int iq = 0; iq < 4; ++iq) tmax[iq] = s[iq];
#pragma unroll
        for (int off = 32; off; off >>= 1)
#pragma unroll
            for (int iq = 0; iq < 4; ++iq) tmax[iq] = fmaxf(tmax[iq], __shfl_xor(tmax[iq], off));
        float p[4], psum[4], alpha[4];
#pragma unroll
        for (int iq = 0; iq < 4; ++iq) {
            float m_new = fmaxf(m_run[iq], tmax[iq]);
            p[iq] = __expf(s[iq] - m_new);
            alpha[iq] = __expf(m_run[iq] - m_new);
            m_run[iq] = m_new;
            psum[iq] = p[iq];
        }
#pragma unroll
        for (int off = 32; off; off >>= 1)
#pragma unroll
            for (int iq = 0; iq < 4; ++iq) psum[iq] += __shfl_xor(psum[iq], off);
#pragma unroll
        for (int iq = 0; iq < 4; ++iq) {
            l_run[iq] = l_run[iq] * alpha[iq] + psum[iq];
            o_acc[iq] *= alpha[iq];
        }
        {
            float4v pv;
#pragma unroll
            for (int iq = 0; iq < 4; ++iq) pv[iq] = p[iq];
            *(float4v*)(&p_lds[wid][lane * 4]) = pv;
        }
        __syncthreads();
        // ---- PV: lane = d ----
#pragma unroll 4
        for (int kk = 0; kk < 64; ++kk) {
            float vv = __bfloat162float(vp[(size_t)(kt + kk) * stride]);
            float4v pv = *(const float4v*)(&p_lds[wid][kk * 4]);
#pragma unroll
            for (int iq = 0; iq < 4; ++iq) o_acc[iq] += pv[iq] * vv;
        }
        __syncthreads();
    }
#pragma unroll
    for (int iq = 0; iq < 4; ++iq)
        o[(size_t)(b * L_ + q0 + iq) * C_ + h * D_ + lane] = __float2bfloat16(o_acc[iq] / l_run[iq]);
}

// ---------------------------------------------------------------------------
extern "C" void kernel_launch(void* const* d_in, const int* in_sizes, int n_in,
                              void* d_out, int out_size, void* d_ws, size_t ws_size,
                              hipStream_t stream) {
    const float* feats  = (const float*)d_in[0];
    const float* mod    = (const float*)d_in[1];
    const float* w_mod  = (const float*)d_in[2];
    const float* b_mod  = (const float*)d_in[3];
    const float* w_qkv  = (const float*)d_in[4];
    const float* b_qkv  = (const float*)d_in[5];
    const float* w_proj = (const float*)d_in[6];
    const float* b_proj = (const float*)d_in[7];
    const float* w_fc1  = (const float*)d_in[8];
    const float* b_fc1  = (const float*)d_in[9];
    const float* w_fc2  = (const float*)d_in[10];
    const float* b_fc2  = (const float*)d_in[11];

    const int M = B_ * L_;          // 4096

    // Workspace (peak ~40.1 MB, liveness-overlaid):
    //   m:     [0, 48K)        fp32 [2,6144]
    //   slotB: [48K, +24M)     qkv bf16 (3-4), then x1 fp32 16MB (5-8)
    //   slotA: [48K+24M, +8M)  h1 (2-3), o (4-5), h2 (6-7)  bf16 [4096,1024]
    //   slotC: [48K+32M, +8M)  hf chunk bf16 [4096,1024] (step 7)
    char* ws = (char*)d_ws;
    float* m_ws = (float*)ws;
    char* slotB = ws + 49152;
    __hip_bfloat16* qkv_ws = (__hip_bfloat16*)slotB;
    float* x1_ws           = (float*)slotB;
    __hip_bfloat16* slotA  = (__hip_bfloat16*)(slotB + (size_t)M * 3 * C_ * 2);
    __hip_bfloat16* slotC  = slotA + (size_t)M * C_;

    // 1. modulation vectors
    k_mod<<<dim3(24), 256, 0, stream>>>(mod, w_mod, b_mod, m_ws);
    // 2. h1 = modulate(LN(feats))
    k_ln_mod<<<M, 256, 0, stream>>>(feats, m_ws, 0, 1024, slotA);
    // 3. qkv = h1 @ w_qkv + b_qkv
    k_gemm_mfma<<<dim3(3 * C_ / 128, M / 128), 256, 0, stream>>>(
        slotA, C_, w_qkv, 3 * C_, b_qkv, M, 3 * C_, C_, 0, 0,
        nullptr, nullptr, qkv_ws, nullptr);
    // 4. o = attention(qkv)
    k_attn<<<B_ * H_ * (L_ / 4) / 4, 256, 0, stream>>>(qkv_ws, slotA);
    // 5. x1 = feats + (o @ w_proj + b_proj) * g_a
    k_gemm_mfma<<<dim3(C_ / 128, M / 128), 256, 0, stream>>>(
        slotA, C_, w_proj, C_, b_proj, M, C_, C_, 0, 2,
        m_ws + 2 * C_, feats, nullptr, x1_ws);
    // 6. h2 = modulate(LN(x1))
    k_ln_mod<<<M, 256, 0, stream>>>(x1_ws, m_ws, 3 * C_, 4 * C_, slotA);
    // 7. FFN, K-chunked (4 chunks of 1024 hidden):
    for (int c = 0; c < 4; ++c) {
        k_gemm_mfma<<<dim3(C_ / 128, M / 128), 256, 0, stream>>>(
            slotA, C_, w_fc1 + c * C_, 4 * C_, b_fc1 + c * C_, M, C_, C_, 1, 0,
            nullptr, nullptr, slotC, nullptr);
        if (c < 3) {
            k_gemm_mfma<<<dim3(C_ / 128, M / 128), 256, 0, stream>>>(
                slotC, C_, w_fc2 + (size_t)c * C_ * C_, C_, (c == 0 ? b_fc2 : nullptr),
                M, C_, C_, 0, 3, m_ws + 5 * C_, nullptr, nullptr, x1_ws);
        } else {
            k_gemm_mfma<<<dim3(C_ / 128, M / 128), 256, 0, stream>>>(
                slotC, C_, w_fc2 + (size_t)c * C_ * C_, C_, nullptr,
                M, C_, C_, 0, 2, m_ws + 5 * C_, x1_ws, nullptr, (float*)d_out);
        }
    }
}

// Round 5
// 989.951 us; speedup vs baseline: 10.4915x; 1.7420x over previous
//
#include <hip/hip_runtime.h>
#include <hip/hip_bf16.h>
#include <math.h>

#define B_ 2
#define L_ 2048
#define C_ 1024
#define H_ 16
#define D_ 64

typedef __attribute__((ext_vector_type(8))) short short8;   // 8 bf16 = 16B (4 VGPRs)
typedef __attribute__((ext_vector_type(4))) float float4v;

__device__ inline float bf2f(short s) {
    union { __hip_bfloat16 h; short s; } u; u.s = s; return __bfloat162float(u.h);
}
__device__ inline short f2bs(float f) {
    union { __hip_bfloat16 h; short s; } u; u.h = __float2bfloat16(f); return u.s;
}

// ---------------------------------------------------------------------------
// Kernel 1: m = silu(mod) @ w_mod + b_mod   → fp32 [2, 6144] in ws
__global__ __launch_bounds__(256) void k_mod(const float* __restrict__ mod,
                                             const float* __restrict__ w_mod,
                                             const float* __restrict__ b_mod,
                                             float* __restrict__ m_out) {
    __shared__ float a_s[2][C_];
    for (int i = threadIdx.x; i < 2 * C_; i += 256) {
        float a = mod[i];
        a_s[i >> 10][i & (C_ - 1)] = a / (1.f + __expf(-a));  // silu
    }
    __syncthreads();
    int j = blockIdx.x * 256 + threadIdx.x;  // 0..6143
    float acc0 = b_mod[j];
    float acc1 = acc0;
    for (int k = 0; k < C_; ++k) {
        float w = w_mod[(size_t)k * (6 * C_) + j];
        acc0 += a_s[0][k] * w;
        acc1 += a_s[1][k] * w;
    }
    m_out[j] = acc0;
    m_out[6 * C_ + j] = acc1;
}

// ---------------------------------------------------------------------------
// Kernel 2: LayerNorm (eps 1e-6, no affine) + adaLN modulate → bf16 h
__global__ __launch_bounds__(256) void k_ln_mod(const float* __restrict__ x,
                                                const float* __restrict__ mvec,
                                                int off_sh, int off_sc,
                                                __hip_bfloat16* __restrict__ h_out) {
    int row = blockIdx.x;       // 0..4095
    int b = row / L_;
    int t = threadIdx.x;
    float v[4];
    float s = 0.f, ss = 0.f;
#pragma unroll
    for (int i = 0; i < 4; ++i) {
        int c = t + i * 256;
        float val = x[(size_t)row * C_ + c];
        v[i] = val; s += val; ss += val * val;
    }
#pragma unroll
    for (int o = 32; o; o >>= 1) { s += __shfl_xor(s, o); ss += __shfl_xor(ss, o); }
    __shared__ float red[2][4];
    int wid = t >> 6, lane = t & 63;
    if (lane == 0) { red[0][wid] = s; red[1][wid] = ss; }
    __syncthreads();
    s  = red[0][0] + red[0][1] + red[0][2] + red[0][3];
    ss = red[1][0] + red[1][1] + red[1][2] + red[1][3];
    float mean = s * (1.f / C_);
    float var  = ss * (1.f / C_) - mean * mean;
    float rstd = rsqrtf(var + 1e-6f);
#pragma unroll
    for (int i = 0; i < 4; ++i) {
        int c = t + i * 256;
        float sc = mvec[b * (6 * C_) + off_sc + c];
        float sh = mvec[b * (6 * C_) + off_sh + c];
        float hn = (v[i] - mean) * rstd;
        h_out[(size_t)row * C_ + c] = __float2bfloat16(hn * (1.f + sc) + sh);
    }
}

// ---------------------------------------------------------------------------
// Kernel 3: MFMA GEMM  v = A[M,K](lda, bf16) @ W[K,N](ldw, fp32→bf16) + bias(f32)
// 128x128 tile, BK=32, 4 waves (2x2 of 64x64), mfma_f32_16x16x32_bf16.
//   act==1: gelu_exact;  emode 0: store; 2: resid_f + v*gate; 3: out_f += v*gate
__global__ __launch_bounds__(256) void k_gemm_mfma(
        const __hip_bfloat16* __restrict__ A, int lda,
        const float* __restrict__ Wm, int ldw,
        const float* __restrict__ bias,
        int M, int N, int K, int act, int emode,
        const float* __restrict__ gate,
        const float* __restrict__ resid_f,
        __hip_bfloat16* __restrict__ out_bf,
        float* __restrict__ out_f) {
    __shared__ short A_lds[128 * 40];
    __shared__ short B_lds[128 * 40];
    const int t = threadIdx.x;
    const int lane = t & 63;
    const int w = t >> 6;
    const int wm = w >> 1, wn = w & 1;
    const int quad = lane >> 4, l16 = lane & 15;
    const int m0 = blockIdx.y * 128;
    const int n0 = blockIdx.x * 128;

    float4v acc[4][4] = {};

    const int a_row0 = t >> 2;             // +0 / +64
    const int a_kc = (t & 3) * 8;
    const int b_n = t & 127;
    const int b_kg = (t >> 7) * 16;

    for (int k0 = 0; k0 < K; k0 += 32) {
        __syncthreads();
#pragma unroll
        for (int rep = 0; rep < 2; ++rep) {
            int row = a_row0 + rep * 64;
            short8 av = *(const short8*)(A + (size_t)(m0 + row) * lda + k0 + a_kc);
            *(short8*)(&A_lds[row * 40 + a_kc]) = av;
        }
#pragma unroll
        for (int rep = 0; rep < 2; ++rep) {
            int kb = b_kg + rep * 8;
            short8 bv;
#pragma unroll
            for (int j = 0; j < 8; ++j)
                bv[j] = f2bs(Wm[(size_t)(k0 + kb + j) * ldw + n0 + b_n]);
            *(short8*)(&B_lds[b_n * 40 + kb]) = bv;
        }
        __syncthreads();
        short8 af[4], bf[4];
#pragma unroll
        for (int mi = 0; mi < 4; ++mi)
            af[mi] = *(const short8*)(&A_lds[(wm * 64 + mi * 16 + l16) * 40 + quad * 8]);
#pragma unroll
        for (int ni = 0; ni < 4; ++ni)
            bf[ni] = *(const short8*)(&B_lds[(wn * 64 + ni * 16 + l16) * 40 + quad * 8]);
#pragma unroll
        for (int mi = 0; mi < 4; ++mi)
#pragma unroll
            for (int ni = 0; ni < 4; ++ni)
                acc[mi][ni] = __builtin_amdgcn_mfma_f32_16x16x32_bf16(
                    af[mi], bf[ni], acc[mi][ni], 0, 0, 0);
    }

#pragma unroll
    for (int mi = 0; mi < 4; ++mi) {
#pragma unroll
        for (int ni = 0; ni < 4; ++ni) {
#pragma unroll
            for (int r = 0; r < 4; ++r) {
                int m = m0 + wm * 64 + mi * 16 + quad * 4 + r;
                int n = n0 + wn * 64 + ni * 16 + l16;
                float v = acc[mi][ni][r] + (bias ? bias[n] : 0.f);
                if (act == 1) v = 0.5f * v * (1.f + erff(v * 0.70710678118654752440f));
                if (emode == 2) {
                    float g = gate[(m >> 11) * (6 * C_) + n];
                    v = resid_f[(size_t)m * N + n] + v * g;
                } else if (emode == 3) {
                    float g = gate[(m >> 11) * (6 * C_) + n];
                    out_f[(size_t)m * N + n] += v * g;
                    continue;
                }
                if (out_f) out_f[(size_t)m * N + n] = v;
                else       out_bf[(size_t)m * N + n] = __float2bfloat16(v);
            }
        }
    }
}

// ---------------------------------------------------------------------------
// Kernel 4: flash attention with MFMA. Block = 4 waves = 64 queries of one
// (b,h); wave owns 16 queries. Per 64-key tile: QK^T via 8 MFMAs (K staged
// [key][d]), online softmax in C-layout (shuffles within 16-lane groups),
// P→LDS (C-layout → A-layout transform), PV via 8 MFMAs (V staged transposed
// [d][key]). All LDS rows padded to 72 shorts (stride 36 dwords → even bank
// spread for b128).
__global__ __launch_bounds__(256) void k_attn(const __hip_bfloat16* __restrict__ qkv,
                                              __hip_bfloat16* __restrict__ o) {
    __shared__ short K_lds[64 * 72];        // [key][d]
    __shared__ short V_lds[64 * 72];        // [d][key]  (transposed)
    __shared__ short P_lds[4][16 * 72];     // per wave: [q][key]

    const int t = threadIdx.x;
    const int lane = t & 63;
    const int w = t >> 6;
    const int quad = lane >> 4, l16 = lane & 15;

    const int blk = blockIdx.x;             // 0..1023
    const int q_blk = (blk & 31) * 64;
    const int bh = blk >> 5;
    const int h = bh & (H_ - 1);
    const int b = bh >> 4;

    const size_t stride = 3 * C_;
    const __hip_bfloat16* base = qkv + (size_t)b * L_ * stride + h * D_;

    // Q A-fragments, register resident: Q[m=l16][k = c*32 + quad*8 + j]
    short8 qf[2];
    {
        const __hip_bfloat16* qrow = base + (size_t)(q_blk + w * 16 + l16) * stride;
        qf[0] = *(const short8*)(qrow + quad * 8);
        qf[1] = *(const short8*)(qrow + 32 + quad * 8);
    }

    float4v o_acc[4];                       // [dtile] C-frags: o_acc[dt][r]
    float m_run[4], l_run[4];
#pragma unroll
    for (int r = 0; r < 4; ++r) { m_run[r] = -3.0e38f; l_run[r] = 0.f; }
#pragma unroll
    for (int dt = 0; dt < 4; ++dt) o_acc[dt] = (float4v){0.f, 0.f, 0.f, 0.f};

    const int s_key = t >> 2;               // staging: 4 threads per key row
    const int s_dg = (t & 3) * 16;
    const __hip_bfloat16* kg = base + C_;
    const __hip_bfloat16* vg = base + 2 * C_;

    for (int kt = 0; kt < L_; kt += 64) {
        __syncthreads();
        // ---- stage K [key][d] and V transposed [d][key] ----
        {
            const __hip_bfloat16* kr = kg + (size_t)(kt + s_key) * stride + s_dg;
            short8 k0 = *(const short8*)(kr);
            short8 k1 = *(const short8*)(kr + 8);
            *(short8*)(&K_lds[s_key * 72 + s_dg]) = k0;
            *(short8*)(&K_lds[s_key * 72 + s_dg + 8]) = k1;
            const __hip_bfloat16* vr = vg + (size_t)(kt + s_key) * stride + s_dg;
            short8 v0 = *(const short8*)(vr);
            short8 v1 = *(const short8*)(vr + 8);
#pragma unroll
            for (int j = 0; j < 8; ++j) {
                V_lds[(s_dg + j) * 72 + s_key] = v0[j];
                V_lds[(s_dg + 8 + j) * 72 + s_key] = v1[j];
            }
        }
        __syncthreads();

        // ---- S = Q K^T  (B-frag = rows of K, X·Y^T symmetry) ----
        float4v sacc[4];
#pragma unroll
        for (int kb = 0; kb < 4; ++kb) {
            sacc[kb] = (float4v){0.f, 0.f, 0.f, 0.f};
            short8 kf0 = *(const short8*)(&K_lds[(kb * 16 + l16) * 72 + quad * 8]);
            short8 kf1 = *(const short8*)(&K_lds[(kb * 16 + l16) * 72 + 32 + quad * 8]);
            sacc[kb] = __builtin_amdgcn_mfma_f32_16x16x32_bf16(qf[0], kf0, sacc[kb], 0, 0, 0);
            sacc[kb] = __builtin_amdgcn_mfma_f32_16x16x32_bf16(qf[1], kf1, sacc[kb], 0, 0, 0);
        }

        // ---- online softmax; row q = quad*4 + r, cols spread over l16 + kb ----
#pragma unroll
        for (int r = 0; r < 4; ++r) {
            float s0 = sacc[0][r] * 0.125f;
            float s1 = sacc[1][r] * 0.125f;
            float s2 = sacc[2][r] * 0.125f;
            float s3 = sacc[3][r] * 0.125f;
            float tmax = fmaxf(fmaxf(s0, s1), fmaxf(s2, s3));
#pragma unroll
            for (int off = 1; off < 16; off <<= 1)
                tmax = fmaxf(tmax, __shfl_xor(tmax, off));
            float m_new = fmaxf(m_run[r], tmax);
            float alpha = __expf(m_run[r] - m_new);
            m_run[r] = m_new;
            float p0 = __expf(s0 - m_new);
            float p1 = __expf(s1 - m_new);
            float p2 = __expf(s2 - m_new);
            float p3 = __expf(s3 - m_new);
            short* prow = &P_lds[w][(quad * 4 + r) * 72];
            prow[l16]      = f2bs(p0);
            prow[16 + l16] = f2bs(p1);
            prow[32 + l16] = f2bs(p2);
            prow[48 + l16] = f2bs(p3);
            float psum = (p0 + p1) + (p2 + p3);
#pragma unroll
            for (int off = 1; off < 16; off <<= 1)
                psum += __shfl_xor(psum, off);
            l_run[r] = l_run[r] * alpha + psum;
#pragma unroll
            for (int dt = 0; dt < 4; ++dt) o_acc[dt][r] *= alpha;
        }

        // ---- O += P V  (A-frag = P rows from LDS, B-frag = rows of V^T) ----
        short8 pf0 = *(const short8*)(&P_lds[w][l16 * 72 + quad * 8]);
        short8 pf1 = *(const short8*)(&P_lds[w][l16 * 72 + 32 + quad * 8]);
#pragma unroll
        for (int dt = 0; dt < 4; ++dt) {
            short8 vf0 = *(const short8*)(&V_lds[(dt * 16 + l16) * 72 + quad * 8]);
            short8 vf1 = *(const short8*)(&V_lds[(dt * 16 + l16) * 72 + 32 + quad * 8]);
            o_acc[dt] = __builtin_amdgcn_mfma_f32_16x16x32_bf16(pf0, vf0, o_acc[dt], 0, 0, 0);
            o_acc[dt] = __builtin_amdgcn_mfma_f32_16x16x32_bf16(pf1, vf1, o_acc[dt], 0, 0, 0);
        }
    }

    // ---- normalize + store:  o[q][h*64 + d] ----
#pragma unroll
    for (int dt = 0; dt < 4; ++dt) {
#pragma unroll
        for (int r = 0; r < 4; ++r) {
            int q = q_blk + w * 16 + quad * 4 + r;
            o[(size_t)(b * L_ + q) * C_ + h * D_ + dt * 16 + l16] =
                __float2bfloat16(o_acc[dt][r] / l_run[r]);
        }
    }
}

// ---------------------------------------------------------------------------
extern "C" void kernel_launch(void* const* d_in, const int* in_sizes, int n_in,
                              void* d_out, int out_size, void* d_ws, size_t ws_size,
                              hipStream_t stream) {
    const float* feats  = (const float*)d_in[0];
    const float* mod    = (const float*)d_in[1];
    const float* w_mod  = (const float*)d_in[2];
    const float* b_mod  = (const float*)d_in[3];
    const float* w_qkv  = (const float*)d_in[4];
    const float* b_qkv  = (const float*)d_in[5];
    const float* w_proj = (const float*)d_in[6];
    const float* b_proj = (const float*)d_in[7];
    const float* w_fc1  = (const float*)d_in[8];
    const float* b_fc1  = (const float*)d_in[9];
    const float* w_fc2  = (const float*)d_in[10];
    const float* b_fc2  = (const float*)d_in[11];

    const int M = B_ * L_;          // 4096

    // Workspace (peak ~40.1 MB, liveness-overlaid):
    //   m:     [0, 48K)        fp32 [2,6144]
    //   slotB: [48K, +24M)     qkv bf16 (3-4), then x1 fp32 16MB (5-8)
    //   slotA: [48K+24M, +8M)  h1 (2-3), o (4-5), h2 (6-7)  bf16 [4096,1024]
    //   slotC: [48K+32M, +8M)  hf chunk bf16 [4096,1024] (step 7)
    char* ws = (char*)d_ws;
    float* m_ws = (float*)ws;
    char* slotB = ws + 49152;
    __hip_bfloat16* qkv_ws = (__hip_bfloat16*)slotB;
    float* x1_ws           = (float*)slotB;
    __hip_bfloat16* slotA  = (__hip_bfloat16*)(slotB + (size_t)M * 3 * C_ * 2);
    __hip_bfloat16* slotC  = slotA + (size_t)M * C_;

    // 1. modulation vectors
    k_mod<<<dim3(24), 256, 0, stream>>>(mod, w_mod, b_mod, m_ws);
    // 2. h1 = modulate(LN(feats))
    k_ln_mod<<<M, 256, 0, stream>>>(feats, m_ws, 0, 1024, slotA);
    // 3. qkv = h1 @ w_qkv + b_qkv
    k_gemm_mfma<<<dim3(3 * C_ / 128, M / 128), 256, 0, stream>>>(
        slotA, C_, w_qkv, 3 * C_, b_qkv, M, 3 * C_, C_, 0, 0,
        nullptr, nullptr, qkv_ws, nullptr);
    // 4. o = attention(qkv)
    k_attn<<<B_ * H_ * (L_ / 64), 256, 0, stream>>>(qkv_ws, slotA);
    // 5. x1 = feats + (o @ w_proj + b_proj) * g_a
    k_gemm_mfma<<<dim3(C_ / 128, M / 128), 256, 0, stream>>>(
        slotA, C_, w_proj, C_, b_proj, M, C_, C_, 0, 2,
        m_ws + 2 * C_, feats, nullptr, x1_ws);
    // 6. h2 = modulate(LN(x1))
    k_ln_mod<<<M, 256, 0, stream>>>(x1_ws, m_ws, 3 * C_, 4 * C_, slotA);
    // 7. FFN, K-chunked (4 chunks of 1024 hidden):
    for (int c = 0; c < 4; ++c) {
        k_gemm_mfma<<<dim3(C_ / 128, M / 128), 256, 0, stream>>>(
            slotA, C_, w_fc1 + c * C_, 4 * C_, b_fc1 + c * C_, M, C_, C_, 1, 0,
            nullptr, nullptr, slotC, nullptr);
        if (c < 3) {
            k_gemm_mfma<<<dim3(C_ / 128, M / 128), 256, 0, stream>>>(
                slotC, C_, w_fc2 + (size_t)c * C_ * C_, C_, (c == 0 ? b_fc2 : nullptr),
                M, C_, C_, 0, 3, m_ws + 5 * C_, nullptr, nullptr, x1_ws);
        } else {
            k_gemm_mfma<<<dim3(C_ / 128, M / 128), 256, 0, stream>>>(
                slotC, C_, w_fc2 + (size_t)c * C_ * C_, C_, nullptr,
                M, C_, C_, 0, 2, m_ws + 5 * C_, x1_ws, nullptr, (float*)d_out);
        }
    }
}

// Round 6
// 614.483 us; speedup vs baseline: 16.9021x; 1.6110x over previous
//
#include <hip/hip_runtime.h>
#include <hip/hip_bf16.h>
#include <math.h>

#define B_ 2
#define L_ 2048
#define C_ 1024
#define H_ 16
#define D_ 64

typedef __attribute__((ext_vector_type(8))) short short8;   // 8 bf16 = 16B (4 VGPRs)
typedef __attribute__((ext_vector_type(4))) float float4v;

__device__ inline short f2bs(float f) {
    union { __hip_bfloat16 h; short s; } u; u.h = __float2bfloat16(f); return u.s;
}

// ---------------------------------------------------------------------------
// k_mod2: m = silu(mod) @ w_mod + b_mod, split-K (4 segs of 256) + atomicAdd.
// m_out must be zeroed first. grid (24, 4), 256 thr.
__global__ __launch_bounds__(256) void k_mod2(const float* __restrict__ mod,
                                              const float* __restrict__ w_mod,
                                              const float* __restrict__ b_mod,
                                              float* __restrict__ m_out) {
    __shared__ float a_s[2][256];
    const int t = threadIdx.x;
    const int seg = blockIdx.y;
    for (int i = t; i < 512; i += 256) {
        float a = mod[(i >> 8) * C_ + seg * 256 + (i & 255)];
        a_s[i >> 8][i & 255] = a / (1.f + __expf(-a));  // silu
    }
    __syncthreads();
    int j = blockIdx.x * 256 + t;  // 0..6143
    float acc0 = (seg == 0) ? b_mod[j] : 0.f;
    float acc1 = acc0;
    for (int k = 0; k < 256; ++k) {
        float w = w_mod[(size_t)(seg * 256 + k) * (6 * C_) + j];
        acc0 += a_s[0][k] * w;
        acc1 += a_s[1][k] * w;
    }
    atomicAdd(&m_out[j], acc0);
    atomicAdd(&m_out[6 * C_ + j], acc1);
}

// ---------------------------------------------------------------------------
// k_wt: transpose+convert weight fp32 [K][N] → bf16 [N][K]. 64x64 tiles.
__global__ __launch_bounds__(256) void k_wt(const float* __restrict__ W,
                                            short* __restrict__ WT,
                                            int K, int N) {
    __shared__ short T[64][72];
    const int t = threadIdx.x;
    const int n0 = blockIdx.x * 64, k0 = blockIdx.y * 64;
    {
        int kr = t >> 2, nc = (t & 3) * 16;
        const float* src = W + (size_t)(k0 + kr) * N + n0 + nc;
#pragma unroll
        for (int j = 0; j < 16; ++j) T[kr][nc + j] = f2bs(src[j]);
    }
    __syncthreads();
    {
        int nr = t >> 2, kc = (t & 3) * 16;
        short8 o0, o1;
#pragma unroll
        for (int j = 0; j < 8; ++j) { o0[j] = T[kc + j][nr]; o1[j] = T[kc + 8 + j][nr]; }
        short* dst = WT + (size_t)(n0 + nr) * K + k0 + kc;
        *(short8*)dst = o0;
        *(short8*)(dst + 8) = o1;
    }
}

// ---------------------------------------------------------------------------
// Kernel 2: LayerNorm (eps 1e-6, no affine) + adaLN modulate → bf16 h
__global__ __launch_bounds__(256) void k_ln_mod(const float* __restrict__ x,
                                                const float* __restrict__ mvec,
                                                int off_sh, int off_sc,
                                                __hip_bfloat16* __restrict__ h_out) {
    int row = blockIdx.x;       // 0..4095
    int b = row / L_;
    int t = threadIdx.x;
    float v[4];
    float s = 0.f, ss = 0.f;
#pragma unroll
    for (int i = 0; i < 4; ++i) {
        int c = t + i * 256;
        float val = x[(size_t)row * C_ + c];
        v[i] = val; s += val; ss += val * val;
    }
#pragma unroll
    for (int o = 32; o; o >>= 1) { s += __shfl_xor(s, o); ss += __shfl_xor(ss, o); }
    __shared__ float red[2][4];
    int wid = t >> 6, lane = t & 63;
    if (lane == 0) { red[0][wid] = s; red[1][wid] = ss; }
    __syncthreads();
    s  = red[0][0] + red[0][1] + red[0][2] + red[0][3];
    ss = red[1][0] + red[1][1] + red[1][2] + red[1][3];
    float mean = s * (1.f / C_);
    float var  = ss * (1.f / C_) - mean * mean;
    float rstd = rsqrtf(var + 1e-6f);
#pragma unroll
    for (int i = 0; i < 4; ++i) {
        int c = t + i * 256;
        float sc = mvec[b * (6 * C_) + off_sc + c];
        float sh = mvec[b * (6 * C_) + off_sh + c];
        float hn = (v[i] - mean) * rstd;
        h_out[(size_t)row * C_ + c] = __float2bfloat16(hn * (1.f + sc) + sh);
    }
}

// ---------------------------------------------------------------------------
// Shared GEMM epilogue
__device__ inline void gemm_epilogue(float v, int m, int n, int N, int act, int emode,
                                     const float* __restrict__ gate,
                                     const float* __restrict__ resid_f,
                                     __hip_bfloat16* __restrict__ out_bf,
                                     float* __restrict__ out_f) {
    if (act == 1) v = 0.5f * v * (1.f + erff(v * 0.70710678118654752440f));
    if (emode == 2) {
        float g = gate[(m >> 11) * (6 * C_) + n];
        v = resid_f[(size_t)m * N + n] + v * g;
    } else if (emode == 3) {
        float g = gate[(m >> 11) * (6 * C_) + n];
        out_f[(size_t)m * N + n] += v * g;
        return;
    }
    if (out_f) out_f[(size_t)m * N + n] = v;
    else       out_bf[(size_t)m * N + n] = __float2bfloat16(v);
}

// ---------------------------------------------------------------------------
// k_gemm_bf16w: v = A[M,K](lda, bf16) @ WT[N,K](ldw=K, bf16, pre-transposed)
// Tile BM x BN = (WM*MI*16) x (WN*NI*16), 4 waves, BK=32.
template<int WM, int WN, int MI, int NI>
__global__ __launch_bounds__(256) void k_gemm_bf16w(
        const __hip_bfloat16* __restrict__ A, int lda,
        const short* __restrict__ WT, int ldw,
        const float* __restrict__ bias,
        int M, int N, int K, int act, int emode,
        const float* __restrict__ gate,
        const float* __restrict__ resid_f,
        __hip_bfloat16* __restrict__ out_bf,
        float* __restrict__ out_f) {
    constexpr int BM = WM * MI * 16;
    constexpr int BN = WN * NI * 16;
    __shared__ short A_lds[BM * 40];
    __shared__ short B_lds[BN * 40];
    const int t = threadIdx.x;
    const int lane = t & 63;
    const int w = t >> 6;
    const int wm = w / WN, wn = w % WN;
    const int quad = lane >> 4, l16 = lane & 15;
    const int m0 = blockIdx.y * BM;
    const int n0 = blockIdx.x * BN;

    float4v acc[MI][NI] = {};

    const int s_row = t >> 2;
    const int s_kc = (t & 3) * 8;

    for (int k0 = 0; k0 < K; k0 += 32) {
        __syncthreads();
#pragma unroll
        for (int rep = 0; rep < BM / 64; ++rep) {
            int row = s_row + rep * 64;
            short8 av = *(const short8*)(A + (size_t)(m0 + row) * lda + k0 + s_kc);
            *(short8*)(&A_lds[row * 40 + s_kc]) = av;
        }
#pragma unroll
        for (int rep = 0; rep < BN / 64; ++rep) {
            int row = s_row + rep * 64;
            short8 bv = *(const short8*)(WT + (size_t)(n0 + row) * ldw + k0 + s_kc);
            *(short8*)(&B_lds[row * 40 + s_kc]) = bv;
        }
        __syncthreads();
        short8 af[MI], bf[NI];
#pragma unroll
        for (int mi = 0; mi < MI; ++mi)
            af[mi] = *(const short8*)(&A_lds[(wm * MI * 16 + mi * 16 + l16) * 40 + quad * 8]);
#pragma unroll
        for (int ni = 0; ni < NI; ++ni)
            bf[ni] = *(const short8*)(&B_lds[(wn * NI * 16 + ni * 16 + l16) * 40 + quad * 8]);
#pragma unroll
        for (int mi = 0; mi < MI; ++mi)
#pragma unroll
            for (int ni = 0; ni < NI; ++ni)
                acc[mi][ni] = __builtin_amdgcn_mfma_f32_16x16x32_bf16(
                    af[mi], bf[ni], acc[mi][ni], 0, 0, 0);
    }

#pragma unroll
    for (int mi = 0; mi < MI; ++mi)
#pragma unroll
        for (int ni = 0; ni < NI; ++ni)
#pragma unroll
            for (int r = 0; r < 4; ++r) {
                int m = m0 + wm * MI * 16 + mi * 16 + quad * 4 + r;
                int n = n0 + wn * NI * 16 + ni * 16 + l16;
                float v = acc[mi][ni][r] + (bias ? bias[n] : 0.f);
                gemm_epilogue(v, m, n, N, act, emode, gate, resid_f, out_bf, out_f);
            }
}

// ---------------------------------------------------------------------------
// Fallback GEMM (Round-5 verified): W fp32 [K][N], converted during staging.
__global__ __launch_bounds__(256) void k_gemm_f32w(
        const __hip_bfloat16* __restrict__ A, int lda,
        const float* __restrict__ Wm, int ldw,
        const float* __restrict__ bias,
        int M, int N, int K, int act, int emode,
        const float* __restrict__ gate,
        const float* __restrict__ resid_f,
        __hip_bfloat16* __restrict__ out_bf,
        float* __restrict__ out_f) {
    __shared__ short A_lds[128 * 40];
    __shared__ short B_lds[128 * 40];
    const int t = threadIdx.x;
    const int lane = t & 63;
    const int w = t >> 6;
    const int wm = w >> 1, wn = w & 1;
    const int quad = lane >> 4, l16 = lane & 15;
    const int m0 = blockIdx.y * 128;
    const int n0 = blockIdx.x * 128;
    float4v acc[4][4] = {};
    const int a_row0 = t >> 2;
    const int a_kc = (t & 3) * 8;
    const int b_n = t & 127;
    const int b_kg = (t >> 7) * 16;
    for (int k0 = 0; k0 < K; k0 += 32) {
        __syncthreads();
#pragma unroll
        for (int rep = 0; rep < 2; ++rep) {
            int row = a_row0 + rep * 64;
            short8 av = *(const short8*)(A + (size_t)(m0 + row) * lda + k0 + a_kc);
            *(short8*)(&A_lds[row * 40 + a_kc]) = av;
        }
#pragma unroll
        for (int rep = 0; rep < 2; ++rep) {
            int kb = b_kg + rep * 8;
            short8 bv;
#pragma unroll
            for (int j = 0; j < 8; ++j)
                bv[j] = f2bs(Wm[(size_t)(k0 + kb + j) * ldw + n0 + b_n]);
            *(short8*)(&B_lds[b_n * 40 + kb]) = bv;
        }
        __syncthreads();
        short8 af[4], bf[4];
#pragma unroll
        for (int mi = 0; mi < 4; ++mi)
            af[mi] = *(const short8*)(&A_lds[(wm * 64 + mi * 16 + l16) * 40 + quad * 8]);
#pragma unroll
        for (int ni = 0; ni < 4; ++ni)
            bf[ni] = *(const short8*)(&B_lds[(wn * 64 + ni * 16 + l16) * 40 + quad * 8]);
#pragma unroll
        for (int mi = 0; mi < 4; ++mi)
#pragma unroll
            for (int ni = 0; ni < 4; ++ni)
                acc[mi][ni] = __builtin_amdgcn_mfma_f32_16x16x32_bf16(
                    af[mi], bf[ni], acc[mi][ni], 0, 0, 0);
    }
#pragma unroll
    for (int mi = 0; mi < 4; ++mi)
#pragma unroll
        for (int ni = 0; ni < 4; ++ni)
#pragma unroll
            for (int r = 0; r < 4; ++r) {
                int m = m0 + wm * 64 + mi * 16 + quad * 4 + r;
                int n = n0 + wn * 64 + ni * 16 + l16;
                float v = acc[mi][ni][r] + (bias ? bias[n] : 0.f);
                gemm_epilogue(v, m, n, N, act, emode, gate, resid_f, out_bf, out_f);
            }
}

// ---------------------------------------------------------------------------
// Kernel 4: flash attention with MFMA (V staged conflict-free, 2 keys/dword).
__global__ __launch_bounds__(256) void k_attn(const __hip_bfloat16* __restrict__ qkv,
                                              __hip_bfloat16* __restrict__ o) {
    __shared__ short K_lds[64 * 72];        // [key][d], stride 72
    __shared__ short V_lds[64 * 66];        // [d][key], stride 66
    __shared__ short P_lds[4][16 * 72];     // per wave: [q][key]

    const int t = threadIdx.x;
    const int lane = t & 63;
    const int w = t >> 6;
    const int quad = lane >> 4, l16 = lane & 15;

    const int blk = blockIdx.x;             // 0..1023
    const int q_blk = (blk & 31) * 64;
    const int bh = blk >> 5;
    const int h = bh & (H_ - 1);
    const int b = bh >> 4;

    const size_t stride = 3 * C_;
    const __hip_bfloat16* base = qkv + (size_t)b * L_ * stride + h * D_;

    short8 qf[2];
    {
        const __hip_bfloat16* qrow = base + (size_t)(q_blk + w * 16 + l16) * stride;
        qf[0] = *(const short8*)(qrow + quad * 8);
        qf[1] = *(const short8*)(qrow + 32 + quad * 8);
    }

    float4v o_acc[4];
    float m_run[4], l_run[4];
#pragma unroll
    for (int r = 0; r < 4; ++r) { m_run[r] = -3.0e38f; l_run[r] = 0.f; }
#pragma unroll
    for (int dt = 0; dt < 4; ++dt) o_acc[dt] = (float4v){0.f, 0.f, 0.f, 0.f};

    const int s_key = t >> 2;               // K staging: 4 thr/key row
    const int s_dg = (t & 3) * 16;
    const int v_kp = (t >> 3) * 2;          // V staging: key pair (0..62)
    const int v_dg = (t & 7) * 8;           // 8 d's per thread
    const __hip_bfloat16* kg = base + C_;
    const __hip_bfloat16* vg = base + 2 * C_;

    for (int kt = 0; kt < L_; kt += 64) {
        __syncthreads();
        {   // K: [key][d], 16B copies
            const __hip_bfloat16* kr = kg + (size_t)(kt + s_key) * stride + s_dg;
            *(short8*)(&K_lds[s_key * 72 + s_dg]) = *(const short8*)(kr);
            *(short8*)(&K_lds[s_key * 72 + s_dg + 8]) = *(const short8*)(kr + 8);
        }
        {   // V: transpose to [d][key], 2 keys packed per dword write
            const __hip_bfloat16* vr0 = vg + (size_t)(kt + v_kp) * stride + v_dg;
            short8 v0 = *(const short8*)(vr0);
            short8 v1 = *(const short8*)(vr0 + stride);
            unsigned int* V32 = (unsigned int*)V_lds;
#pragma unroll
            for (int j = 0; j < 8; ++j)
                V32[(v_dg + j) * 33 + (v_kp >> 1)] =
                    (unsigned int)(unsigned short)v0[j] |
                    ((unsigned int)(unsigned short)v1[j] << 16);
        }
        __syncthreads();

        // ---- S = Q K^T ----
        float4v sacc[4];
#pragma unroll
        for (int kb = 0; kb < 4; ++kb) {
            sacc[kb] = (float4v){0.f, 0.f, 0.f, 0.f};
            short8 kf0 = *(const short8*)(&K_lds[(kb * 16 + l16) * 72 + quad * 8]);
            short8 kf1 = *(const short8*)(&K_lds[(kb * 16 + l16) * 72 + 32 + quad * 8]);
            sacc[kb] = __builtin_amdgcn_mfma_f32_16x16x32_bf16(qf[0], kf0, sacc[kb], 0, 0, 0);
            sacc[kb] = __builtin_amdgcn_mfma_f32_16x16x32_bf16(qf[1], kf1, sacc[kb], 0, 0, 0);
        }

        // ---- online softmax ----
#pragma unroll
        for (int r = 0; r < 4; ++r) {
            float s0 = sacc[0][r] * 0.125f;
            float s1 = sacc[1][r] * 0.125f;
            float s2 = sacc[2][r] * 0.125f;
            float s3 = sacc[3][r] * 0.125f;
            float tmax = fmaxf(fmaxf(s0, s1), fmaxf(s2, s3));
#pragma unroll
            for (int off = 1; off < 16; off <<= 1)
                tmax = fmaxf(tmax, __shfl_xor(tmax, off));
            float m_new = fmaxf(m_run[r], tmax);
            float alpha = __expf(m_run[r] - m_new);
            m_run[r] = m_new;
            float p0 = __expf(s0 - m_new);
            float p1 = __expf(s1 - m_new);
            float p2 = __expf(s2 - m_new);
            float p3 = __expf(s3 - m_new);
            short* prow = &P_lds[w][(quad * 4 + r) * 72];
            prow[l16]      = f2bs(p0);
            prow[16 + l16] = f2bs(p1);
            prow[32 + l16] = f2bs(p2);
            prow[48 + l16] = f2bs(p3);
            float psum = (p0 + p1) + (p2 + p3);
#pragma unroll
            for (int off = 1; off < 16; off <<= 1)
                psum += __shfl_xor(psum, off);
            l_run[r] = l_run[r] * alpha + psum;
#pragma unroll
            for (int dt = 0; dt < 4; ++dt) o_acc[dt][r] *= alpha;
        }

        // ---- O += P V ----
        short8 pf0 = *(const short8*)(&P_lds[w][l16 * 72 + quad * 8]);
        short8 pf1 = *(const short8*)(&P_lds[w][l16 * 72 + 32 + quad * 8]);
#pragma unroll
        for (int dt = 0; dt < 4; ++dt) {
            short8 vf0 = *(const short8*)(&V_lds[(dt * 16 + l16) * 66 + quad * 8]);
            short8 vf1 = *(const short8*)(&V_lds[(dt * 16 + l16) * 66 + 32 + quad * 8]);
            o_acc[dt] = __builtin_amdgcn_mfma_f32_16x16x32_bf16(pf0, vf0, o_acc[dt], 0, 0, 0);
            o_acc[dt] = __builtin_amdgcn_mfma_f32_16x16x32_bf16(pf1, vf1, o_acc[dt], 0, 0, 0);
        }
    }

#pragma unroll
    for (int dt = 0; dt < 4; ++dt)
#pragma unroll
        for (int r = 0; r < 4; ++r) {
            int q = q_blk + w * 16 + quad * 4 + r;
            o[(size_t)(b * L_ + q) * C_ + h * D_ + dt * 16 + l16] =
                __float2bfloat16(o_acc[dt][r] / l_run[r]);
        }
}

// ---------------------------------------------------------------------------
extern "C" void kernel_launch(void* const* d_in, const int* in_sizes, int n_in,
                              void* d_out, int out_size, void* d_ws, size_t ws_size,
                              hipStream_t stream) {
    const float* feats  = (const float*)d_in[0];
    const float* mod    = (const float*)d_in[1];
    const float* w_mod  = (const float*)d_in[2];
    const float* b_mod  = (const float*)d_in[3];
    const float* w_qkv  = (const float*)d_in[4];
    const float* b_qkv  = (const float*)d_in[5];
    const float* w_proj = (const float*)d_in[6];
    const float* b_proj = (const float*)d_in[7];
    const float* w_fc1  = (const float*)d_in[8];
    const float* b_fc1  = (const float*)d_in[9];
    const float* w_fc2  = (const float*)d_in[10];
    const float* b_fc2  = (const float*)d_in[11];

    const int M = B_ * L_;          // 4096
    char* ws = (char*)d_ws;
    float* m_ws = (float*)ws;

    // Big layout (needs ~88.05 MB):
    //   m 48K | wT 24MB (qkvT 6, projT 2, fc1T 8, fc2T 8) | slotB 24MB
    //   (qkv bf16 → x1 fp32) | slotA 8MB (h1/o/h2) | hf 32MB bf16
    const size_t WT_BYTES = (size_t)(3 * C_ * C_ + C_ * C_ + 4 * C_ * C_ + 4 * C_ * C_) * 2;
    const size_t BIG_NEED = 49152 + WT_BYTES + (size_t)M * 3 * C_ * 2
                          + (size_t)M * C_ * 2 + (size_t)M * 4 * C_ * 2;

    if (ws_size >= BIG_NEED) {
        short* wqkvT = (short*)(ws + 49152);
        short* wprojT = wqkvT + (size_t)3 * C_ * C_;
        short* wfc1T  = wprojT + (size_t)C_ * C_;
        short* wfc2T  = wfc1T + (size_t)4 * C_ * C_;
        char* slotB = (char*)(wfc2T + (size_t)4 * C_ * C_);
        __hip_bfloat16* qkv_ws = (__hip_bfloat16*)slotB;
        float* x1_ws           = (float*)slotB;
        __hip_bfloat16* slotA  = (__hip_bfloat16*)(slotB + (size_t)M * 3 * C_ * 2);
        __hip_bfloat16* hf_ws  = slotA + (size_t)M * C_;

        // 0. weight prep (bf16, transposed [N][K])
        k_wt<<<dim3(3 * C_ / 64, C_ / 64), 256, 0, stream>>>(w_qkv, wqkvT, C_, 3 * C_);
        k_wt<<<dim3(C_ / 64, C_ / 64), 256, 0, stream>>>(w_proj, wprojT, C_, C_);
        k_wt<<<dim3(4 * C_ / 64, C_ / 64), 256, 0, stream>>>(w_fc1, wfc1T, C_, 4 * C_);
        k_wt<<<dim3(C_ / 64, 4 * C_ / 64), 256, 0, stream>>>(w_fc2, wfc2T, 4 * C_, C_);
        // 1. modulation vectors (split-K + atomics; zero first)
        hipMemsetAsync(m_ws, 0, 2 * 6 * C_ * sizeof(float), stream);
        k_mod2<<<dim3(24, 4), 256, 0, stream>>>(mod, w_mod, b_mod, m_ws);
        // 2. h1 = modulate(LN(feats))
        k_ln_mod<<<M, 256, 0, stream>>>(feats, m_ws, 0, 1024, slotA);
        // 3. qkv = h1 @ w_qkv + b_qkv   (128x128, 768 blocks)
        k_gemm_bf16w<2, 2, 4, 4><<<dim3(3 * C_ / 128, M / 128), 256, 0, stream>>>(
            slotA, C_, wqkvT, C_, b_qkv, M, 3 * C_, C_, 0, 0,
            nullptr, nullptr, qkv_ws, nullptr);
        // 4. o = attention(qkv)
        k_attn<<<B_ * H_ * (L_ / 64), 256, 0, stream>>>(qkv_ws, slotA);
        // 5. x1 = feats + (o @ w_proj + b_proj) * g_a   (128x64, 512 blocks)
        k_gemm_bf16w<4, 1, 2, 4><<<dim3(C_ / 64, M / 128), 256, 0, stream>>>(
            slotA, C_, wprojT, C_, b_proj, M, C_, C_, 0, 2,
            m_ws + 2 * C_, feats, nullptr, x1_ws);
        // 6. h2 = modulate(LN(x1))
        k_ln_mod<<<M, 256, 0, stream>>>(x1_ws, m_ws, 3 * C_, 4 * C_, slotA);
        // 7. hf = gelu(h2 @ w_fc1 + b_fc1)   (128x128, 1024 blocks)
        k_gemm_bf16w<2, 2, 4, 4><<<dim3(4 * C_ / 128, M / 128), 256, 0, stream>>>(
            slotA, C_, wfc1T, C_, b_fc1, M, 4 * C_, C_, 1, 0,
            nullptr, nullptr, hf_ws, nullptr);
        // 8. out = x1 + (hf @ w_fc2 + b_fc2) * g_m   (128x64, K=4096, 512 blocks)
        k_gemm_bf16w<4, 1, 2, 4><<<dim3(C_ / 64, M / 128), 256, 0, stream>>>(
            hf_ws, 4 * C_, wfc2T, 4 * C_, b_fc2, M, C_, 4 * C_, 0, 2,
            m_ws + 5 * C_, x1_ws, nullptr, (float*)d_out);
    } else {
        // ---- Round-5 fallback (fp32 weights, chunked FFN, peak ~40.1 MB) ----
        char* slotB = ws + 49152;
        __hip_bfloat16* qkv_ws = (__hip_bfloat16*)slotB;
        float* x1_ws           = (float*)slotB;
        __hip_bfloat16* slotA  = (__hip_bfloat16*)(slotB + (size_t)M * 3 * C_ * 2);
        __hip_bfloat16* slotC  = slotA + (size_t)M * C_;

        hipMemsetAsync(m_ws, 0, 2 * 6 * C_ * sizeof(float), stream);
        k_mod2<<<dim3(24, 4), 256, 0, stream>>>(mod, w_mod, b_mod, m_ws);
        k_ln_mod<<<M, 256, 0, stream>>>(feats, m_ws, 0, 1024, slotA);
        k_gemm_f32w<<<dim3(3 * C_ / 128, M / 128), 256, 0, stream>>>(
            slotA, C_, w_qkv, 3 * C_, b_qkv, M, 3 * C_, C_, 0, 0,
            nullptr, nullptr, qkv_ws, nullptr);
        k_attn<<<B_ * H_ * (L_ / 64), 256, 0, stream>>>(qkv_ws, slotA);
        k_gemm_f32w<<<dim3(C_ / 128, M / 128), 256, 0, stream>>>(
            slotA, C_, w_proj, C_, b_proj, M, C_, C_, 0, 2,
            m_ws + 2 * C_, feats, nullptr, x1_ws);
        k_ln_mod<<<M, 256, 0, stream>>>(x1_ws, m_ws, 3 * C_, 4 * C_, slotA);
        for (int c = 0; c < 4; ++c) {
            k_gemm_f32w<<<dim3(C_ / 128, M / 128), 256, 0, stream>>>(
                slotA, C_, w_fc1 + c * C_, 4 * C_, b_fc1 + c * C_, M, C_, C_, 1, 0,
                nullptr, nullptr, slotC, nullptr);
            if (c < 3) {
                k_gemm_f32w<<<dim3(C_ / 128, M / 128), 256, 0, stream>>>(
                    slotC, C_, w_fc2 + (size_t)c * C_ * C_, C_, (c == 0 ? b_fc2 : nullptr),
                    M, C_, C_, 0, 3, m_ws + 5 * C_, nullptr, nullptr, x1_ws);
            } else {
                k_gemm_f32w<<<dim3(C_ / 128, M / 128), 256, 0, stream>>>(
                    slotC, C_, w_fc2 + (size_t)c * C_ * C_, C_, nullptr,
                    M, C_, C_, 0, 2, m_ws + 5 * C_, x1_ws, nullptr, (float*)d_out);
            }
        }
    }
}

// Round 7
// 593.230 us; speedup vs baseline: 17.5077x; 1.0358x over previous
//
#include <hip/hip_runtime.h>
#include <hip/hip_bf16.h>
#include <math.h>

#define B_ 2
#define L_ 2048
#define C_ 1024
#define H_ 16
#define D_ 64

typedef __attribute__((ext_vector_type(8))) short short8;   // 8 bf16 = 16B (4 VGPRs)
typedef __attribute__((ext_vector_type(4))) float float4v;

__device__ inline short f2bs(float f) {
    union { __hip_bfloat16 h; short s; } u; u.h = __float2bfloat16(f); return u.s;
}

// async 16B global→LDS DMA (dest = wave-uniform base + lane*16)
#define GL2LDS(gp, lp)                                                         \
    __builtin_amdgcn_global_load_lds(                                          \
        (const __attribute__((address_space(1))) void*)(gp),                   \
        (__attribute__((address_space(3))) void*)(lp), 16, 0, 0)

// ---------------------------------------------------------------------------
// k_mod2: m = silu(mod) @ w_mod + b_mod, split-K (4 segs of 256) + atomicAdd.
__global__ __launch_bounds__(256) void k_mod2(const float* __restrict__ mod,
                                              const float* __restrict__ w_mod,
                                              const float* __restrict__ b_mod,
                                              float* __restrict__ m_out) {
    __shared__ float a_s[2][256];
    const int t = threadIdx.x;
    const int seg = blockIdx.y;
    for (int i = t; i < 512; i += 256) {
        float a = mod[(i >> 8) * C_ + seg * 256 + (i & 255)];
        a_s[i >> 8][i & 255] = a / (1.f + __expf(-a));  // silu
    }
    __syncthreads();
    int j = blockIdx.x * 256 + t;  // 0..6143
    float acc0 = (seg == 0) ? b_mod[j] : 0.f;
    float acc1 = acc0;
    for (int k = 0; k < 256; ++k) {
        float w = w_mod[(size_t)(seg * 256 + k) * (6 * C_) + j];
        acc0 += a_s[0][k] * w;
        acc1 += a_s[1][k] * w;
    }
    atomicAdd(&m_out[j], acc0);
    atomicAdd(&m_out[6 * C_ + j], acc1);
}

// ---------------------------------------------------------------------------
// k_wt: transpose+convert weight fp32 [K][N] → bf16 [N][K]. 64x64 tiles.
__global__ __launch_bounds__(256) void k_wt(const float* __restrict__ W,
                                            short* __restrict__ WT,
                                            int K, int N) {
    __shared__ short T[64][72];
    const int t = threadIdx.x;
    const int n0 = blockIdx.x * 64, k0 = blockIdx.y * 64;
    {
        int kr = t >> 2, nc = (t & 3) * 16;
        const float* src = W + (size_t)(k0 + kr) * N + n0 + nc;
#pragma unroll
        for (int j = 0; j < 16; ++j) T[kr][nc + j] = f2bs(src[j]);
    }
    __syncthreads();
    {
        int nr = t >> 2, kc = (t & 3) * 16;
        short8 o0, o1;
#pragma unroll
        for (int j = 0; j < 8; ++j) { o0[j] = T[kc + j][nr]; o1[j] = T[kc + 8 + j][nr]; }
        short* dst = WT + (size_t)(n0 + nr) * K + k0 + kc;
        *(short8*)dst = o0;
        *(short8*)(dst + 8) = o1;
    }
}

// ---------------------------------------------------------------------------
// Kernel 2: LayerNorm (eps 1e-6, no affine) + adaLN modulate → bf16 h
__global__ __launch_bounds__(256) void k_ln_mod(const float* __restrict__ x,
                                                const float* __restrict__ mvec,
                                                int off_sh, int off_sc,
                                                __hip_bfloat16* __restrict__ h_out) {
    int row = blockIdx.x;       // 0..4095
    int b = row / L_;
    int t = threadIdx.x;
    float v[4];
    float s = 0.f, ss = 0.f;
#pragma unroll
    for (int i = 0; i < 4; ++i) {
        int c = t + i * 256;
        float val = x[(size_t)row * C_ + c];
        v[i] = val; s += val; ss += val * val;
    }
#pragma unroll
    for (int o = 32; o; o >>= 1) { s += __shfl_xor(s, o); ss += __shfl_xor(ss, o); }
    __shared__ float red[2][4];
    int wid = t >> 6, lane = t & 63;
    if (lane == 0) { red[0][wid] = s; red[1][wid] = ss; }
    __syncthreads();
    s  = red[0][0] + red[0][1] + red[0][2] + red[0][3];
    ss = red[1][0] + red[1][1] + red[1][2] + red[1][3];
    float mean = s * (1.f / C_);
    float var  = ss * (1.f / C_) - mean * mean;
    float rstd = rsqrtf(var + 1e-6f);
#pragma unroll
    for (int i = 0; i < 4; ++i) {
        int c = t + i * 256;
        float sc = mvec[b * (6 * C_) + off_sc + c];
        float sh = mvec[b * (6 * C_) + off_sh + c];
        float hn = (v[i] - mean) * rstd;
        h_out[(size_t)row * C_ + c] = __float2bfloat16(hn * (1.f + sc) + sh);
    }
}

// ---------------------------------------------------------------------------
// Shared GEMM epilogue
__device__ inline void gemm_epilogue(float v, int m, int n, int N, int act, int emode,
                                     const float* __restrict__ gate,
                                     const float* __restrict__ resid_f,
                                     __hip_bfloat16* __restrict__ out_bf,
                                     float* __restrict__ out_f) {
    if (act == 1) v = 0.5f * v * (1.f + erff(v * 0.70710678118654752440f));
    if (emode == 2) {
        float g = gate[(m >> 11) * (6 * C_) + n];
        v = resid_f[(size_t)m * N + n] + v * g;
    }
    if (out_f) out_f[(size_t)m * N + n] = v;
    else       out_bf[(size_t)m * N + n] = __float2bfloat16(v);
}

// ---------------------------------------------------------------------------
// k_gemm_async: v = A[M,K](lda, bf16) @ WT[N,K](ldw=K, bf16, pre-transposed)
// Tile BM x BN, 4 waves, BK=32. Staging via global_load_lds width=16 (async
// DMA, no VGPR round-trip). LDS layout: unpadded 32-short rows, 16B chunks
// swizzled pos=(g+(row>>1))&3 → frag ds_read_b128 is 2-way-per-bank (free),
// and staging satisfies the wave-uniform-base+lane*16 DMA constraint.
template<int WM, int WN, int MI, int NI>
__global__ __launch_bounds__(256) void k_gemm_async(
        const __hip_bfloat16* __restrict__ A, int lda,
        const short* __restrict__ WT, int ldw,
        const float* __restrict__ bias,
        int M, int N, int K, int act, int emode,
        const float* __restrict__ gate,
        const float* __restrict__ resid_f,
        __hip_bfloat16* __restrict__ out_bf,
        float* __restrict__ out_f) {
    constexpr int BM = WM * MI * 16;
    constexpr int BN = WN * NI * 16;
    __shared__ __align__(16) short A_lds[BM * 32];
    __shared__ __align__(16) short B_lds[BN * 32];
    const int t = threadIdx.x;
    const int lane = t & 63;
    const int w = t >> 6;
    const int wm = w / WN, wn = w % WN;
    const int quad = lane >> 4, l16 = lane & 15;
    const int m0 = blockIdx.y * BM;
    const int n0 = blockIdx.x * BN;

    float4v acc[MI][NI] = {};

    for (int k0 = 0; k0 < K; k0 += 32) {
        __syncthreads();   // prior frag reads done before DMA overwrites
        // ---- stage A: BM rows x 32 k, swizzled chunks, async DMA ----
#pragma unroll
        for (int rep = 0; rep < BM / 64; ++rep) {
            int c = rep * 256 + t;                 // chunk id
            int row = c >> 2;
            int g = ((c & 3) - (row >> 1)) & 3;    // logical k-group
            const __hip_bfloat16* gp = A + (size_t)(m0 + row) * lda + k0 + g * 8;
            GL2LDS(gp, &A_lds[(rep * 256 + (t & ~63)) * 8]);
        }
        // ---- stage B ----
#pragma unroll
        for (int rep = 0; rep < BN / 64; ++rep) {
            int c = rep * 256 + t;
            int row = c >> 2;
            int g = ((c & 3) - (row >> 1)) & 3;
            const short* gp = WT + (size_t)(n0 + row) * ldw + k0 + g * 8;
            GL2LDS(gp, &B_lds[(rep * 256 + (t & ~63)) * 8]);
        }
        __syncthreads();   // drains DMA (compiler emits vmcnt(0) before barrier)
        // ---- fragments + MFMA ----
        short8 af[MI], bf[NI];
#pragma unroll
        for (int mi = 0; mi < MI; ++mi) {
            int r = wm * MI * 16 + mi * 16 + l16;
            af[mi] = *(const short8*)(&A_lds[(r * 4 + ((quad + (r >> 1)) & 3)) * 8]);
        }
#pragma unroll
        for (int ni = 0; ni < NI; ++ni) {
            int r = wn * NI * 16 + ni * 16 + l16;
            bf[ni] = *(const short8*)(&B_lds[(r * 4 + ((quad + (r >> 1)) & 3)) * 8]);
        }
#pragma unroll
        for (int mi = 0; mi < MI; ++mi)
#pragma unroll
            for (int ni = 0; ni < NI; ++ni)
                acc[mi][ni] = __builtin_amdgcn_mfma_f32_16x16x32_bf16(
                    af[mi], bf[ni], acc[mi][ni], 0, 0, 0);
    }

#pragma unroll
    for (int mi = 0; mi < MI; ++mi)
#pragma unroll
        for (int ni = 0; ni < NI; ++ni)
#pragma unroll
            for (int r = 0; r < 4; ++r) {
                int m = m0 + wm * MI * 16 + mi * 16 + quad * 4 + r;
                int n = n0 + wn * NI * 16 + ni * 16 + l16;
                float v = acc[mi][ni][r] + (bias ? bias[n] : 0.f);
                gemm_epilogue(v, m, n, N, act, emode, gate, resid_f, out_bf, out_f);
            }
}

// ---------------------------------------------------------------------------
// Kernel 4: flash attention with MFMA (unchanged from Round 6).
__global__ __launch_bounds__(256) void k_attn(const __hip_bfloat16* __restrict__ qkv,
                                              __hip_bfloat16* __restrict__ o) {
    __shared__ short K_lds[64 * 72];        // [key][d], stride 72
    __shared__ short V_lds[64 * 66];        // [d][key], stride 66
    __shared__ short P_lds[4][16 * 72];     // per wave: [q][key]

    const int t = threadIdx.x;
    const int lane = t & 63;
    const int w = t >> 6;
    const int quad = lane >> 4, l16 = lane & 15;

    const int blk = blockIdx.x;             // 0..1023
    const int q_blk = (blk & 31) * 64;
    const int bh = blk >> 5;
    const int h = bh & (H_ - 1);
    const int b = bh >> 4;

    const size_t stride = 3 * C_;
    const __hip_bfloat16* base = qkv + (size_t)b * L_ * stride + h * D_;

    short8 qf[2];
    {
        const __hip_bfloat16* qrow = base + (size_t)(q_blk + w * 16 + l16) * stride;
        qf[0] = *(const short8*)(qrow + quad * 8);
        qf[1] = *(const short8*)(qrow + 32 + quad * 8);
    }

    float4v o_acc[4];
    float m_run[4], l_run[4];
#pragma unroll
    for (int r = 0; r < 4; ++r) { m_run[r] = -3.0e38f; l_run[r] = 0.f; }
#pragma unroll
    for (int dt = 0; dt < 4; ++dt) o_acc[dt] = (float4v){0.f, 0.f, 0.f, 0.f};

    const int s_key = t >> 2;
    const int s_dg = (t & 3) * 16;
    const int v_kp = (t >> 3) * 2;
    const int v_dg = (t & 7) * 8;
    const __hip_bfloat16* kg = base + C_;
    const __hip_bfloat16* vg = base + 2 * C_;

    for (int kt = 0; kt < L_; kt += 64) {
        __syncthreads();
        {   // K: [key][d], 16B copies
            const __hip_bfloat16* kr = kg + (size_t)(kt + s_key) * stride + s_dg;
            *(short8*)(&K_lds[s_key * 72 + s_dg]) = *(const short8*)(kr);
            *(short8*)(&K_lds[s_key * 72 + s_dg + 8]) = *(const short8*)(kr + 8);
        }
        {   // V: transpose to [d][key], 2 keys packed per dword write
            const __hip_bfloat16* vr0 = vg + (size_t)(kt + v_kp) * stride + v_dg;
            short8 v0 = *(const short8*)(vr0);
            short8 v1 = *(const short8*)(vr0 + stride);
            unsigned int* V32 = (unsigned int*)V_lds;
#pragma unroll
            for (int j = 0; j < 8; ++j)
                V32[(v_dg + j) * 33 + (v_kp >> 1)] =
                    (unsigned int)(unsigned short)v0[j] |
                    ((unsigned int)(unsigned short)v1[j] << 16);
        }
        __syncthreads();

        float4v sacc[4];
#pragma unroll
        for (int kb = 0; kb < 4; ++kb) {
            sacc[kb] = (float4v){0.f, 0.f, 0.f, 0.f};
            short8 kf0 = *(const short8*)(&K_lds[(kb * 16 + l16) * 72 + quad * 8]);
            short8 kf1 = *(const short8*)(&K_lds[(kb * 16 + l16) * 72 + 32 + quad * 8]);
            sacc[kb] = __builtin_amdgcn_mfma_f32_16x16x32_bf16(qf[0], kf0, sacc[kb], 0, 0, 0);
            sacc[kb] = __builtin_amdgcn_mfma_f32_16x16x32_bf16(qf[1], kf1, sacc[kb], 0, 0, 0);
        }

#pragma unroll
        for (int r = 0; r < 4; ++r) {
            float s0 = sacc[0][r] * 0.125f;
            float s1 = sacc[1][r] * 0.125f;
            float s2 = sacc[2][r] * 0.125f;
            float s3 = sacc[3][r] * 0.125f;
            float tmax = fmaxf(fmaxf(s0, s1), fmaxf(s2, s3));
#pragma unroll
            for (int off = 1; off < 16; off <<= 1)
                tmax = fmaxf(tmax, __shfl_xor(tmax, off));
            float m_new = fmaxf(m_run[r], tmax);
            float alpha = __expf(m_run[r] - m_new);
            m_run[r] = m_new;
            float p0 = __expf(s0 - m_new);
            float p1 = __expf(s1 - m_new);
            float p2 = __expf(s2 - m_new);
            float p3 = __expf(s3 - m_new);
            short* prow = &P_lds[w][(quad * 4 + r) * 72];
            prow[l16]      = f2bs(p0);
            prow[16 + l16] = f2bs(p1);
            prow[32 + l16] = f2bs(p2);
            prow[48 + l16] = f2bs(p3);
            float psum = (p0 + p1) + (p2 + p3);
#pragma unroll
            for (int off = 1; off < 16; off <<= 1)
                psum += __shfl_xor(psum, off);
            l_run[r] = l_run[r] * alpha + psum;
#pragma unroll
            for (int dt = 0; dt < 4; ++dt) o_acc[dt][r] *= alpha;
        }

        short8 pf0 = *(const short8*)(&P_lds[w][l16 * 72 + quad * 8]);
        short8 pf1 = *(const short8*)(&P_lds[w][l16 * 72 + 32 + quad * 8]);
#pragma unroll
        for (int dt = 0; dt < 4; ++dt) {
            short8 vf0 = *(const short8*)(&V_lds[(dt * 16 + l16) * 66 + quad * 8]);
            short8 vf1 = *(const short8*)(&V_lds[(dt * 16 + l16) * 66 + 32 + quad * 8]);
            o_acc[dt] = __builtin_amdgcn_mfma_f32_16x16x32_bf16(pf0, vf0, o_acc[dt], 0, 0, 0);
            o_acc[dt] = __builtin_amdgcn_mfma_f32_16x16x32_bf16(pf1, vf1, o_acc[dt], 0, 0, 0);
        }
    }

#pragma unroll
    for (int dt = 0; dt < 4; ++dt)
#pragma unroll
        for (int r = 0; r < 4; ++r) {
            int q = q_blk + w * 16 + quad * 4 + r;
            o[(size_t)(b * L_ + q) * C_ + h * D_ + dt * 16 + l16] =
                __float2bfloat16(o_acc[dt][r] / l_run[r]);
        }
}

// ---------------------------------------------------------------------------
extern "C" void kernel_launch(void* const* d_in, const int* in_sizes, int n_in,
                              void* d_out, int out_size, void* d_ws, size_t ws_size,
                              hipStream_t stream) {
    const float* feats  = (const float*)d_in[0];
    const float* mod    = (const float*)d_in[1];
    const float* w_mod  = (const float*)d_in[2];
    const float* b_mod  = (const float*)d_in[3];
    const float* w_qkv  = (const float*)d_in[4];
    const float* b_qkv  = (const float*)d_in[5];
    const float* w_proj = (const float*)d_in[6];
    const float* b_proj = (const float*)d_in[7];
    const float* w_fc1  = (const float*)d_in[8];
    const float* b_fc1  = (const float*)d_in[9];
    const float* w_fc2  = (const float*)d_in[10];
    const float* b_fc2  = (const float*)d_in[11];

    const int M = B_ * L_;          // 4096
    char* ws = (char*)d_ws;
    float* m_ws = (float*)ws;

    // Layout (~88.05 MB, confirmed fits in R6):
    //   m 48K | wT 24MB (qkvT 6, projT 2, fc1T 8, fc2T 8) | slotB 24MB
    //   (qkv bf16 → x1 fp32 16MB) | slotA 8MB (h1/o/h2) | hf 32MB bf16
    short* wqkvT  = (short*)(ws + 49152);
    short* wprojT = wqkvT + (size_t)3 * C_ * C_;
    short* wfc1T  = wprojT + (size_t)C_ * C_;
    short* wfc2T  = wfc1T + (size_t)4 * C_ * C_;
    char* slotB = (char*)(wfc2T + (size_t)4 * C_ * C_);
    __hip_bfloat16* qkv_ws = (__hip_bfloat16*)slotB;
    float* x1_ws           = (float*)slotB;
    __hip_bfloat16* slotA  = (__hip_bfloat16*)(slotB + (size_t)M * 3 * C_ * 2);
    __hip_bfloat16* hf_ws  = slotA + (size_t)M * C_;

    // 0. weight prep (bf16, transposed [N][K])
    k_wt<<<dim3(3 * C_ / 64, C_ / 64), 256, 0, stream>>>(w_qkv, wqkvT, C_, 3 * C_);
    k_wt<<<dim3(C_ / 64, C_ / 64), 256, 0, stream>>>(w_proj, wprojT, C_, C_);
    k_wt<<<dim3(4 * C_ / 64, C_ / 64), 256, 0, stream>>>(w_fc1, wfc1T, C_, 4 * C_);
    k_wt<<<dim3(C_ / 64, 4 * C_ / 64), 256, 0, stream>>>(w_fc2, wfc2T, 4 * C_, C_);
    // 1. modulation vectors (split-K + atomics; zero first)
    hipMemsetAsync(m_ws, 0, 2 * 6 * C_ * sizeof(float), stream);
    k_mod2<<<dim3(24, 4), 256, 0, stream>>>(mod, w_mod, b_mod, m_ws);
    // 2. h1 = modulate(LN(feats))
    k_ln_mod<<<M, 256, 0, stream>>>(feats, m_ws, 0, 1024, slotA);
    // 3. qkv = h1 @ w_qkv + b_qkv   (128x128, 768 blocks)
    k_gemm_async<2, 2, 4, 4><<<dim3(3 * C_ / 128, M / 128), 256, 0, stream>>>(
        slotA, C_, wqkvT, C_, b_qkv, M, 3 * C_, C_, 0, 0,
        nullptr, nullptr, qkv_ws, nullptr);
    // 4. o = attention(qkv)
    k_attn<<<B_ * H_ * (L_ / 64), 256, 0, stream>>>(qkv_ws, slotA);
    // 5. x1 = feats + (o @ w_proj + b_proj) * g_a   (128x64, 512 blocks)
    k_gemm_async<4, 1, 2, 4><<<dim3(C_ / 64, M / 128), 256, 0, stream>>>(
        slotA, C_, wprojT, C_, b_proj, M, C_, C_, 0, 2,
        m_ws + 2 * C_, feats, nullptr, x1_ws);
    // 6. h2 = modulate(LN(x1))
    k_ln_mod<<<M, 256, 0, stream>>>(x1_ws, m_ws, 3 * C_, 4 * C_, slotA);
    // 7. hf = gelu(h2 @ w_fc1 + b_fc1)   (128x128, 1024 blocks)
    k_gemm_async<2, 2, 4, 4><<<dim3(4 * C_ / 128, M / 128), 256, 0, stream>>>(
        slotA, C_, wfc1T, C_, b_fc1, M, 4 * C_, C_, 1, 0,
        nullptr, nullptr, hf_ws, nullptr);
    // 8. out = x1 + (hf @ w_fc2 + b_fc2) * g_m   (128x64, K=4096, 512 blocks)
    k_gemm_async<4, 1, 2, 4><<<dim3(C_ / 64, M / 128), 256, 0, stream>>>(
        hf_ws, 4 * C_, wfc2T, 4 * C_, b_fc2, M, C_, 4 * C_, 0, 2,
        m_ws + 5 * C_, x1_ws, nullptr, (float*)d_out);
}

// Round 8
// 508.751 us; speedup vs baseline: 20.4149x; 1.1661x over previous
//
#include <hip/hip_runtime.h>
#include <hip/hip_bf16.h>
#include <math.h>

#define B_ 2
#define L_ 2048
#define C_ 1024
#define H_ 16
#define D_ 64

typedef __attribute__((ext_vector_type(8))) short short8;   // 8 bf16 = 16B
typedef __attribute__((ext_vector_type(4))) float float4v;

__device__ inline short f2bs(float f) {
    union { __hip_bfloat16 h; short s; } u; u.h = __float2bfloat16(f); return u.s;
}

// async 16B global→LDS DMA (dest = wave-uniform base + lane*16)
#define GL2LDS(gp, lp)                                                         \
    __builtin_amdgcn_global_load_lds(                                          \
        (const __attribute__((address_space(1))) void*)(gp),                   \
        (__attribute__((address_space(3))) void*)(lp), 16, 0, 0)

// ---------------------------------------------------------------------------
// k_mod2: m = silu(mod) @ w_mod + b_mod, split-K (4 segs of 256) + atomicAdd.
__global__ __launch_bounds__(256) void k_mod2(const float* __restrict__ mod,
                                              const float* __restrict__ w_mod,
                                              const float* __restrict__ b_mod,
                                              float* __restrict__ m_out) {
    __shared__ float a_s[2][256];
    const int t = threadIdx.x;
    const int seg = blockIdx.y;
    for (int i = t; i < 512; i += 256) {
        float a = mod[(i >> 8) * C_ + seg * 256 + (i & 255)];
        a_s[i >> 8][i & 255] = a / (1.f + __expf(-a));  // silu
    }
    __syncthreads();
    int j = blockIdx.x * 256 + t;  // 0..6143
    float acc0 = (seg == 0) ? b_mod[j] : 0.f;
    float acc1 = acc0;
    for (int k = 0; k < 256; ++k) {
        float w = w_mod[(size_t)(seg * 256 + k) * (6 * C_) + j];
        acc0 += a_s[0][k] * w;
        acc1 += a_s[1][k] * w;
    }
    atomicAdd(&m_out[j], acc0);
    atomicAdd(&m_out[6 * C_ + j], acc1);
}

// ---------------------------------------------------------------------------
// k_wt: transpose+convert weight fp32 [K][N] → bf16 [N][K]. 64x64 tiles.
__global__ __launch_bounds__(256) void k_wt(const float* __restrict__ W,
                                            short* __restrict__ WT,
                                            int K, int N) {
    __shared__ short T[64][72];
    const int t = threadIdx.x;
    const int n0 = blockIdx.x * 64, k0 = blockIdx.y * 64;
    {
        int kr = t >> 2, nc = (t & 3) * 16;
        const float* src = W + (size_t)(k0 + kr) * N + n0 + nc;
#pragma unroll
        for (int j = 0; j < 16; ++j) T[kr][nc + j] = f2bs(src[j]);
    }
    __syncthreads();
    {
        int nr = t >> 2, kc = (t & 3) * 16;
        short8 o0, o1;
#pragma unroll
        for (int j = 0; j < 8; ++j) { o0[j] = T[kc + j][nr]; o1[j] = T[kc + 8 + j][nr]; }
        short* dst = WT + (size_t)(n0 + nr) * K + k0 + kc;
        *(short8*)dst = o0;
        *(short8*)(dst + 8) = o1;
    }
}

// ---------------------------------------------------------------------------
// k_vt: per-head V transpose. qkv [4096,3072] → vt [bh=32][d=64][L=2048] bf16.
__global__ __launch_bounds__(256) void k_vt(const __hip_bfloat16* __restrict__ qkv,
                                            short* __restrict__ vt) {
    __shared__ short T[64][72];
    const int t = threadIdx.x;
    const int kt = blockIdx.x * 64;
    const int bh = blockIdx.y;
    const int h = bh & (H_ - 1), b = bh >> 4;
    const __hip_bfloat16* src = qkv + ((size_t)(b * L_ + kt)) * (3 * C_) + 2 * C_ + h * D_;
    {
        int kr = t >> 2, dg = (t & 3) * 16;
        const short8* s = (const short8*)(src + (size_t)kr * (3 * C_) + dg);
        *(short8*)&T[kr][dg] = s[0];
        *(short8*)&T[kr][dg + 8] = s[1];
    }
    __syncthreads();
    {
        int dr = t >> 2, kg = (t & 3) * 16;
        short8 o0, o1;
#pragma unroll
        for (int j = 0; j < 8; ++j) { o0[j] = T[kg + j][dr]; o1[j] = T[kg + 8 + j][dr]; }
        short* dst = vt + ((size_t)bh * D_ + dr) * L_ + kt + kg;
        *(short8*)dst = o0;
        *(short8*)(dst + 8) = o1;
    }
}

// ---------------------------------------------------------------------------
// Kernel 2: LayerNorm (eps 1e-6, no affine) + adaLN modulate → bf16 h
__global__ __launch_bounds__(256) void k_ln_mod(const float* __restrict__ x,
                                                const float* __restrict__ mvec,
                                                int off_sh, int off_sc,
                                                __hip_bfloat16* __restrict__ h_out) {
    int row = blockIdx.x;       // 0..4095
    int b = row / L_;
    int t = threadIdx.x;
    float v[4];
    float s = 0.f, ss = 0.f;
#pragma unroll
    for (int i = 0; i < 4; ++i) {
        int c = t + i * 256;
        float val = x[(size_t)row * C_ + c];
        v[i] = val; s += val; ss += val * val;
    }
#pragma unroll
    for (int o = 32; o; o >>= 1) { s += __shfl_xor(s, o); ss += __shfl_xor(ss, o); }
    __shared__ float red[2][4];
    int wid = t >> 6, lane = t & 63;
    if (lane == 0) { red[0][wid] = s; red[1][wid] = ss; }
    __syncthreads();
    s  = red[0][0] + red[0][1] + red[0][2] + red[0][3];
    ss = red[1][0] + red[1][1] + red[1][2] + red[1][3];
    float mean = s * (1.f / C_);
    float var  = ss * (1.f / C_) - mean * mean;
    float rstd = rsqrtf(var + 1e-6f);
#pragma unroll
    for (int i = 0; i < 4; ++i) {
        int c = t + i * 256;
        float sc = mvec[b * (6 * C_) + off_sc + c];
        float sh = mvec[b * (6 * C_) + off_sh + c];
        float hn = (v[i] - mean) * rstd;
        h_out[(size_t)row * C_ + c] = __float2bfloat16(hn * (1.f + sc) + sh);
    }
}

// ---------------------------------------------------------------------------
// Shared GEMM epilogue
__device__ inline void gemm_epilogue(float v, int m, int n, int N, int act, int emode,
                                     const float* __restrict__ gate,
                                     const float* __restrict__ resid_f,
                                     __hip_bfloat16* __restrict__ out_bf,
                                     float* __restrict__ out_f) {
    if (act == 1) v = 0.5f * v * (1.f + erff(v * 0.70710678118654752440f));
    if (emode == 2) {
        float g = gate[(m >> 11) * (6 * C_) + n];
        v = resid_f[(size_t)m * N + n] + v * g;
    }
    if (out_f) out_f[(size_t)m * N + n] = v;
    else       out_bf[(size_t)m * N + n] = __float2bfloat16(v);
}

// ---------------------------------------------------------------------------
// k_gemm_async: A[M,K](bf16) @ WT[N,K](bf16 pre-transposed). BK=64: halves the
// per-K-iter barrier count vs BK=32. LDS rows = 64 shorts = 8×16B chunks,
// XOR-swizzled (phys = logical ^ (row&7)) → conflict-free b128 frag reads and
// DMA-compatible (wave-uniform base + lane*16) staging.
template<int WM, int WN, int MI, int NI>
__global__ __launch_bounds__(256) void k_gemm_async(
        const __hip_bfloat16* __restrict__ A, int lda,
        const short* __restrict__ WT, int ldw,
        const float* __restrict__ bias,
        int M, int N, int K, int act, int emode,
        const float* __restrict__ gate,
        const float* __restrict__ resid_f,
        __hip_bfloat16* __restrict__ out_bf,
        float* __restrict__ out_f) {
    constexpr int BM = WM * MI * 16;
    constexpr int BN = WN * NI * 16;
    __shared__ __align__(16) short A_lds[BM * 64];
    __shared__ __align__(16) short B_lds[BN * 64];
    const int t = threadIdx.x;
    const int lane = t & 63;
    const int w = t >> 6;
    const int wm = w / WN, wn = w % WN;
    const int quad = lane >> 4, l16 = lane & 15;
    const int m0 = blockIdx.y * BM;
    const int n0 = blockIdx.x * BN;

    float4v acc[MI][NI] = {};

    for (int k0 = 0; k0 < K; k0 += 64) {
        __syncthreads();   // prior frag reads done before DMA overwrites
        // ---- stage A: BM rows x 64 k (8 chunks/row, xor-swizzled) ----
#pragma unroll
        for (int rep = 0; rep < BM / 32; ++rep) {
            int p = rep * 256 + t;                 // phys chunk id
            int row = p >> 3;
            int g = (p & 7) ^ (row & 7);           // logical k-group
            const __hip_bfloat16* gp = A + (size_t)(m0 + row) * lda + k0 + g * 8;
            GL2LDS(gp, &A_lds[(rep * 256 + (t & ~63)) * 8]);
        }
        // ---- stage B ----
#pragma unroll
        for (int rep = 0; rep < BN / 32; ++rep) {
            int p = rep * 256 + t;
            int row = p >> 3;
            int g = (p & 7) ^ (row & 7);
            const short* gp = WT + (size_t)(n0 + row) * ldw + k0 + g * 8;
            GL2LDS(gp, &B_lds[(rep * 256 + (t & ~63)) * 8]);
        }
        __syncthreads();   // drains DMA
        // ---- fragments + MFMA (two k-halves) ----
        short8 af[MI][2], bf[NI][2];
#pragma unroll
        for (int mi = 0; mi < MI; ++mi) {
            int r = wm * MI * 16 + mi * 16 + l16;
#pragma unroll
            for (int h = 0; h < 2; ++h)
                af[mi][h] = *(const short8*)(&A_lds[(r * 8 + ((h * 4 + quad) ^ (r & 7))) * 8]);
        }
#pragma unroll
        for (int ni = 0; ni < NI; ++ni) {
            int r = wn * NI * 16 + ni * 16 + l16;
#pragma unroll
            for (int h = 0; h < 2; ++h)
                bf[ni][h] = *(const short8*)(&B_lds[(r * 8 + ((h * 4 + quad) ^ (r & 7))) * 8]);
        }
#pragma unroll
        for (int h = 0; h < 2; ++h)
#pragma unroll
            for (int mi = 0; mi < MI; ++mi)
#pragma unroll
                for (int ni = 0; ni < NI; ++ni)
                    acc[mi][ni] = __builtin_amdgcn_mfma_f32_16x16x32_bf16(
                        af[mi][h], bf[ni][h], acc[mi][ni], 0, 0, 0);
    }

#pragma unroll
    for (int mi = 0; mi < MI; ++mi)
#pragma unroll
        for (int ni = 0; ni < NI; ++ni)
#pragma unroll
            for (int r = 0; r < 4; ++r) {
                int m = m0 + wm * MI * 16 + mi * 16 + quad * 4 + r;
                int n = n0 + wn * NI * 16 + ni * 16 + l16;
                float v = acc[mi][ni][r] + (bias ? bias[n] : 0.f);
                gemm_epilogue(v, m, n, N, act, emode, gate, resid_f, out_bf, out_f);
            }
}

// ---------------------------------------------------------------------------
// Kernel 4: flash attention, MFMA, shift-softmax (no max tracking: constant
// shift cancels in Σpv/Σp; scores bounded |s|≲6 ⇒ no overflow). Row-sums l
// via extra MFMA against all-ones B-frag (D cols all equal Σp, in-lane).
// V^T pre-staged globally → V staging = 2 b128 copies. No shuffles at all.
__global__ __launch_bounds__(256) void k_attn(const __hip_bfloat16* __restrict__ qkv,
                                              const short* __restrict__ vt,
                                              __hip_bfloat16* __restrict__ o) {
    __shared__ short K_lds[64 * 72];        // [key][d], stride 72
    __shared__ short V_lds[64 * 66];        // [d][key], stride 66
    __shared__ short P_lds[4][16 * 68];     // per wave: [q][key], stride 68
                                            // (write banks disjoint per quad)
    const int t = threadIdx.x;
    const int lane = t & 63;
    const int w = t >> 6;
    const int quad = lane >> 4, l16 = lane & 15;

    const int blk = blockIdx.x;             // 0..1023
    const int q_blk = (blk & 31) * 64;
    const int bh = blk >> 5;
    const int h = bh & (H_ - 1);
    const int b = bh >> 4;

    const size_t stride = 3 * C_;
    const __hip_bfloat16* base = qkv + (size_t)b * L_ * stride + h * D_;

    short8 qf[2];
    {
        const __hip_bfloat16* qrow = base + (size_t)(q_blk + w * 16 + l16) * stride;
        qf[0] = *(const short8*)(qrow + quad * 8);
        qf[1] = *(const short8*)(qrow + 32 + quad * 8);
    }
    short8 ones;
#pragma unroll
    for (int j = 0; j < 8; ++j) ones[j] = (short)0x3F80;   // bf16 1.0

    float4v o_acc[4];
    float4v l_acc = (float4v){0.f, 0.f, 0.f, 0.f};
#pragma unroll
    for (int dt = 0; dt < 4; ++dt) o_acc[dt] = (float4v){0.f, 0.f, 0.f, 0.f};

    const int s_key = t >> 2;               // K staging: 4 thr/key row
    const int s_dg = (t & 3) * 16;
    const __hip_bfloat16* kg = base + C_;
    const short* vtb = vt + (size_t)bh * D_ * L_;

    for (int kt = 0; kt < L_; kt += 64) {
        __syncthreads();
        {   // K: [key][d], 16B copies
            const __hip_bfloat16* kr = kg + (size_t)(kt + s_key) * stride + s_dg;
            *(short8*)(&K_lds[s_key * 72 + s_dg]) = *(const short8*)(kr);
            *(short8*)(&K_lds[s_key * 72 + s_dg + 8]) = *(const short8*)(kr + 8);
        }
        {   // V^T: [d][key], 16B copies from pre-transposed global
            const short* vr = vtb + (size_t)s_key * L_ + kt + s_dg;   // s_key = d here
            *(short8*)(&V_lds[s_key * 66 + s_dg]) = *(const short8*)(vr);
            *(short8*)(&V_lds[s_key * 66 + s_dg + 8]) = *(const short8*)(vr + 8);
        }
        __syncthreads();

        // ---- S = Q K^T ----
        float4v sacc[4];
#pragma unroll
        for (int kb = 0; kb < 4; ++kb) {
            sacc[kb] = (float4v){0.f, 0.f, 0.f, 0.f};
            short8 kf0 = *(const short8*)(&K_lds[(kb * 16 + l16) * 72 + quad * 8]);
            short8 kf1 = *(const short8*)(&K_lds[(kb * 16 + l16) * 72 + 32 + quad * 8]);
            sacc[kb] = __builtin_amdgcn_mfma_f32_16x16x32_bf16(qf[0], kf0, sacc[kb], 0, 0, 0);
            sacc[kb] = __builtin_amdgcn_mfma_f32_16x16x32_bf16(qf[1], kf1, sacc[kb], 0, 0, 0);
        }

        // ---- p = exp(s/8 - SHIFT); no reductions ----
#pragma unroll
        for (int r = 0; r < 4; ++r) {
            short* prow = &P_lds[w][(quad * 4 + r) * 68];
            prow[l16]      = f2bs(__expf(fmaf(sacc[0][r], 0.125f, -8.f)));
            prow[16 + l16] = f2bs(__expf(fmaf(sacc[1][r], 0.125f, -8.f)));
            prow[32 + l16] = f2bs(__expf(fmaf(sacc[2][r], 0.125f, -8.f)));
            prow[48 + l16] = f2bs(__expf(fmaf(sacc[3][r], 0.125f, -8.f)));
        }

        // ---- O += P V ; l += P · 1 ----
        short8 pf0 = *(const short8*)(&P_lds[w][l16 * 68 + quad * 8]);
        short8 pf1 = *(const short8*)(&P_lds[w][l16 * 68 + 32 + quad * 8]);
        l_acc = __builtin_amdgcn_mfma_f32_16x16x32_bf16(pf0, ones, l_acc, 0, 0, 0);
        l_acc = __builtin_amdgcn_mfma_f32_16x16x32_bf16(pf1, ones, l_acc, 0, 0, 0);
#pragma unroll
        for (int dt = 0; dt < 4; ++dt) {
            short8 vf0 = *(const short8*)(&V_lds[(dt * 16 + l16) * 66 + quad * 8]);
            short8 vf1 = *(const short8*)(&V_lds[(dt * 16 + l16) * 66 + 32 + quad * 8]);
            o_acc[dt] = __builtin_amdgcn_mfma_f32_16x16x32_bf16(pf0, vf0, o_acc[dt], 0, 0, 0);
            o_acc[dt] = __builtin_amdgcn_mfma_f32_16x16x32_bf16(pf1, vf1, o_acc[dt], 0, 0, 0);
        }
    }

#pragma unroll
    for (int dt = 0; dt < 4; ++dt)
#pragma unroll
        for (int r = 0; r < 4; ++r) {
            int q = q_blk + w * 16 + quad * 4 + r;
            o[(size_t)(b * L_ + q) * C_ + h * D_ + dt * 16 + l16] =
                __float2bfloat16(o_acc[dt][r] / l_acc[r]);
        }
}

// ---------------------------------------------------------------------------
extern "C" void kernel_launch(void* const* d_in, const int* in_sizes, int n_in,
                              void* d_out, int out_size, void* d_ws, size_t ws_size,
                              hipStream_t stream) {
    const float* feats  = (const float*)d_in[0];
    const float* mod    = (const float*)d_in[1];
    const float* w_mod  = (const float*)d_in[2];
    const float* b_mod  = (const float*)d_in[3];
    const float* w_qkv  = (const float*)d_in[4];
    const float* b_qkv  = (const float*)d_in[5];
    const float* w_proj = (const float*)d_in[6];
    const float* b_proj = (const float*)d_in[7];
    const float* w_fc1  = (const float*)d_in[8];
    const float* b_fc1  = (const float*)d_in[9];
    const float* w_fc2  = (const float*)d_in[10];
    const float* b_fc2  = (const float*)d_in[11];

    const int M = B_ * L_;          // 4096
    char* ws = (char*)d_ws;
    float* m_ws = (float*)ws;

    // Layout (~88.05 MB):
    //   m 48K | wT 24MB | slotB 24MB (qkv bf16 → x1 fp32 16MB) |
    //   slotA 8MB (h1/o/h2) | hf 32MB bf16 (doubles as VT 8MB during attn)
    short* wqkvT  = (short*)(ws + 49152);
    short* wprojT = wqkvT + (size_t)3 * C_ * C_;
    short* wfc1T  = wprojT + (size_t)C_ * C_;
    short* wfc2T  = wfc1T + (size_t)4 * C_ * C_;
    char* slotB = (char*)(wfc2T + (size_t)4 * C_ * C_);
    __hip_bfloat16* qkv_ws = (__hip_bfloat16*)slotB;
    float* x1_ws           = (float*)slotB;
    __hip_bfloat16* slotA  = (__hip_bfloat16*)(slotB + (size_t)M * 3 * C_ * 2);
    __hip_bfloat16* hf_ws  = slotA + (size_t)M * C_;
    short* vt_ws           = (short*)hf_ws;   // 8MB, dead outside steps 4

    // 0. weight prep (bf16, transposed [N][K])
    k_wt<<<dim3(3 * C_ / 64, C_ / 64), 256, 0, stream>>>(w_qkv, wqkvT, C_, 3 * C_);
    k_wt<<<dim3(C_ / 64, C_ / 64), 256, 0, stream>>>(w_proj, wprojT, C_, C_);
    k_wt<<<dim3(4 * C_ / 64, C_ / 64), 256, 0, stream>>>(w_fc1, wfc1T, C_, 4 * C_);
    k_wt<<<dim3(C_ / 64, 4 * C_ / 64), 256, 0, stream>>>(w_fc2, wfc2T, 4 * C_, C_);
    // 1. modulation vectors
    hipMemsetAsync(m_ws, 0, 2 * 6 * C_ * sizeof(float), stream);
    k_mod2<<<dim3(24, 4), 256, 0, stream>>>(mod, w_mod, b_mod, m_ws);
    // 2. h1 = modulate(LN(feats))
    k_ln_mod<<<M, 256, 0, stream>>>(feats, m_ws, 0, 1024, slotA);
    // 3. qkv = h1 @ w_qkv + b_qkv
    k_gemm_async<2, 2, 4, 4><<<dim3(3 * C_ / 128, M / 128), 256, 0, stream>>>(
        slotA, C_, wqkvT, C_, b_qkv, M, 3 * C_, C_, 0, 0,
        nullptr, nullptr, qkv_ws, nullptr);
    // 4. V^T precompute + attention
    k_vt<<<dim3(L_ / 64, B_ * H_), 256, 0, stream>>>(qkv_ws, vt_ws);
    k_attn<<<B_ * H_ * (L_ / 64), 256, 0, stream>>>(qkv_ws, vt_ws, slotA);
    // 5. x1 = feats + (o @ w_proj + b_proj) * g_a
    k_gemm_async<4, 1, 2, 4><<<dim3(C_ / 64, M / 128), 256, 0, stream>>>(
        slotA, C_, wprojT, C_, b_proj, M, C_, C_, 0, 2,
        m_ws + 2 * C_, feats, nullptr, x1_ws);
    // 6. h2 = modulate(LN(x1))
    k_ln_mod<<<M, 256, 0, stream>>>(x1_ws, m_ws, 3 * C_, 4 * C_, slotA);
    // 7. hf = gelu(h2 @ w_fc1 + b_fc1)
    k_gemm_async<2, 2, 4, 4><<<dim3(4 * C_ / 128, M / 128), 256, 0, stream>>>(
        slotA, C_, wfc1T, C_, b_fc1, M, 4 * C_, C_, 1, 0,
        nullptr, nullptr, hf_ws, nullptr);
    // 8. out = x1 + (hf @ w_fc2 + b_fc2) * g_m
    k_gemm_async<4, 1, 2, 4><<<dim3(C_ / 64, M / 128), 256, 0, stream>>>(
        hf_ws, 4 * C_, wfc2T, 4 * C_, b_fc2, M, C_, 4 * C_, 0, 2,
        m_ws + 5 * C_, x1_ws, nullptr, (float*)d_out);
}